// Round 14
// baseline (501.184 us; speedup 1.0000x reference)
//
#include <hip/hip_runtime.h>
#include <stdint.h>

#define B_  8
#define S1_ 2048
#define S2_ 2048
#define H_  1024

typedef __attribute__((ext_vector_type(8))) short bf16x8;
typedef __attribute__((ext_vector_type(4))) float f32x4;
typedef unsigned short u16;

__device__ __forceinline__ u16 f2bf(float f){
  union { float f; uint32_t v; } x; x.f = f;
  uint32_t r = x.v + 0x7fffu + ((x.v >> 16) & 1u);
  return (u16)(r >> 16);
}
__device__ __forceinline__ u16 f2h(float f){
  union { _Float16 h; u16 u; } c; c.h = (_Float16)f; return c.u;
}
__device__ __forceinline__ float h2f(u16 u){
  union { _Float16 h; u16 u; } c; c.u = u; return (float)c.h;
}
// packed f32x2 -> bf16x2 (RNE), 1 VALU op for 2 elements
__device__ __forceinline__ uint32_t pk2bf(float lo, float hi){
  uint32_t r;
  asm("v_cvt_pk_bf16_f32 %0, %1, %2" : "=v"(r) : "v"(lo), "v"(hi));
  return r;
}
__device__ __forceinline__ void async16(void* lds, const void* g){
  __builtin_amdgcn_global_load_lds(
      (const __attribute__((address_space(1))) uint32_t*)g,
      (__attribute__((address_space(3))) uint32_t*)lds, 16, 0, 0);
}

// ---------------- fp32 -> bf16 copy ----------------
__global__ __launch_bounds__(256) void k_cvt_bf16(const float* __restrict__ in,
                                                  u16* __restrict__ out, long n){
  long i = ((long)blockIdx.x * 256 + threadIdx.x) * 8;
  const long stride = (long)gridDim.x * 256 * 8;
  for (; i < n; i += stride){
    float4 a = *(const float4*)(in + i);
    float4 b = *(const float4*)(in + i + 4);
    union { bf16x8 v; uint32_t w[4]; } o;
    o.w[0] = pk2bf(a.x, a.y); o.w[1] = pk2bf(a.z, a.w);
    o.w[2] = pk2bf(b.x, b.y); o.w[3] = pk2bf(b.z, b.w);
    *(bf16x8*)(out + i) = o.v;
  }
}

// ------- batched fp32 [R][C] -> bf16 [C][R] transpose (32x32, for W) -------
__global__ __launch_bounds__(256) void k_tcvt(const float* __restrict__ in,
                                              u16* __restrict__ out, int R, int Cc){
  __shared__ u16 t[32][33];
  in  += (long)blockIdx.z * R * Cc;
  out += (long)blockIdx.z * R * Cc;
  const int x = threadIdx.x & 31, y0 = threadIdx.x >> 5;
  const int bx = blockIdx.x * 32, by = blockIdx.y * 32;
  for (int r = y0; r < 32; r += 8) t[r][x] = f2bf(in[(long)(by + r) * Cc + bx + x]);
  __syncthreads();
  for (int r = y0; r < 32; r += 8) out[(long)(bx + r) * R + by + x] = t[x][r];
}

// ------- batched fp32 [R][C] -> bf16 copy AND bf16 transpose, 64x64 tiles -------
__global__ __launch_bounds__(256) void k_cvtT2(const float* __restrict__ in,
                                               u16* __restrict__ out_n,
                                               u16* __restrict__ out_t, int R, int Cc){
  __shared__ u16 t[64][68];
  in    += (long)blockIdx.z * R * Cc;
  out_n += (long)blockIdx.z * R * Cc;
  out_t += (long)blockIdx.z * R * Cc;
  const int tid = threadIdx.x;
  const int r0 = tid >> 4;            // 0..15
  const int c4 = (tid & 15) * 4;      // 0,4,...,60
  const int bx = blockIdx.x * 64;     // col base
  const int by = blockIdx.y * 64;     // row base
#pragma unroll
  for (int it = 0; it < 4; ++it){
    const int r = it*16 + r0;
    float4 v = *(const float4*)(in + (long)(by + r)*Cc + bx + c4);
    u16 b0 = f2bf(v.x), b1 = f2bf(v.y), b2 = f2bf(v.z), b3 = f2bf(v.w);
    ushort4 o; o.x = b0; o.y = b1; o.z = b2; o.w = b3;
    *(ushort4*)(out_n + (long)(by + r)*Cc + bx + c4) = o;
    t[r][c4] = b0; t[r][c4+1] = b1; t[r][c4+2] = b2; t[r][c4+3] = b3;
  }
  __syncthreads();
#pragma unroll
  for (int it = 0; it < 4; ++it){
    const int c = it*16 + r0;         // input col = output row
    ushort4 o;
    o.x = t[c4  ][c]; o.y = t[c4+1][c]; o.z = t[c4+2][c]; o.w = t[c4+3][c];
    *(ushort4*)(out_t + (long)(bx + c)*R + by + c4) = o;
  }
}

// ======= 256x256-tile pipelined bt-GEMM: C = A @ B^T =======
// r14: HYBRID operand feed (r13 + prologue fix). A staged via LDS (4 x 16KB
// buffers, 3-tile prefetch, conflict-free slot swizzle). B-fragments loaded
// DIRECTLY global->register (coalesced dwordx4), prefetched 1 K-tile ahead.
// LEDGER (order-robust): each sub-iter issues exactly 6 vmem ops between two
// "memory"-fenced asm waits; vmcnt(6) retires all older sub-iters' ops
// regardless of intra-window scheduling. PROLOGUE waits vmcnt(0) — a counted
// wait there is NOT order-robust because ordinary vector loads (b0) may be
// scheduled before the global_load_lds ops (r13's NaN).
// T1 XCD chunked swizzle. STATS: scores epilogue emits softmax partials.
// OM: 0 bf16 C, 1 fp16 C, 2 fp32 C.
template<int OM, bool STATS>
__global__ __launch_bounds__(512) void k_gemm256(
    const u16* __restrict__ A, const u16* __restrict__ Bm, void* __restrict__ Cv,
    int M, int N, int K, long sA, long sB, long sC,
    float* __restrict__ rpmax, float* __restrict__ rpsum,
    float* __restrict__ cpmax, float* __restrict__ cpsum)
{
  // ---- XCD chunked swizzle (bijective; total blocks % 8 == 0 by grid design)
  const int GX = gridDim.x, GY = gridDim.y;
  const long plane = (long)GX * GY;
  const long tot = plane * gridDim.z;
  const long lin = blockIdx.x + (long)GX * (blockIdx.y + (long)GY * blockIdx.z);
  const long chunk = tot >> 3;
  const long swz = (lin & 7) * chunk + (lin >> 3);
  const int bz = (int)(swz / plane);
  const int rr = (int)(swz % plane);
  const int by_ = rr / GX, bx_ = rr % GX;

  A += (long)bz * sA; Bm += (long)bz * sB;
  __shared__ u16 lds[4 * 8192];           // 4 bufs x (A 256x32) = 64 KB
  const int tid = threadIdx.x, lane = tid & 63, w = tid >> 6;
  const int wm = w >> 2, wn = w & 3;      // 2 x 4 wave grid
  const int brow = bx_ * 256, bcol = by_ * 256;

  f32x4 acc[8][4];
#pragma unroll
  for (int m=0;m<8;++m)
#pragma unroll
    for (int n=0;n<4;++n) acc[m][n] = (f32x4){0.f,0.f,0.f,0.f};

  const int fr = lane & 15;
  const int hi = lane >> 4;
  const int g8s = (hi ^ ((lane >> 1) & 3)) * 8;   // conflict-free read slot

  // A staging addresses (chunk cc, row=cc>>2, phys slot holds logical ^((row>>1)&3))
  const int cc0 = w*128 + lane;
  const int cc1 = w*128 + 64 + lane;
  const int sl0 = (cc0 & 3) ^ ((cc0 >> 3) & 3);
  const int sl1 = (cc1 & 3) ^ ((cc1 >> 3) & 3);
  const u16* gA0 = A + (long)(brow + (cc0 >> 2)) * K + sl0*8;
  const u16* gA1 = A + (long)(brow + (cc1 >> 2)) * K + sl1*8;
  const int ldA0 = (w*128)*8, ldA1 = (w*128 + 64)*8;

  // B direct-fragment base: row = bcol + wn*64 + n*16 + fr, k = t*32 + hi*8
  const u16* gBF = Bm + (long)(bcol + wn*64 + fr) * K + hi*8;
  const long nK16 = (long)16 * K;

  auto stageA = [&](int buf, int t){
    u16* base = lds + buf*8192;
    async16(base + ldA0, gA0 + t*32);
    async16(base + ldA1, gA1 + t*32);
  };
  auto gloadB = [&](bf16x8* b, int t){
#pragma unroll
    for (int n=0;n<4;++n)
      b[n] = *(const bf16x8*)(gBF + (long)n*nK16 + (long)t*32);
  };
  auto ldfragA = [&](int buf, bf16x8* a){
    const u16* At = lds + buf*8192;
#pragma unroll
    for (int m=0;m<8;++m) a[m] = *(const bf16x8*)(At + (wm*128 + m*16 + fr)*32 + g8s);
  };

  const int NT = K >> 5;                   // even (K multiple of 64)
  bf16x8 a0[8], b0[4], a1[8], b1[4];
  // prologue: stage A tiles 0..2 (6 loads), B frags tile 0 (4 loads).
  // FULL drain — a counted wait here is not robust to load scheduling order.
  stageA(0,0); stageA(1,1); stageA(2,2);
  gloadB(b0, 0);
  asm volatile("s_waitcnt vmcnt(0)" ::: "memory");
  __builtin_amdgcn_s_barrier();
  ldfragA(0, a0);

  for (int t = 0; t < NT; t += 2){
    // ---- sub-iter t (compute a0/b0) ----
    stageA((t+3)&3, min(t+3, NT-1));
    gloadB(b1, min(t+1, NT-1));
    ldfragA((t+1)&3, a1);
    asm volatile("s_waitcnt vmcnt(6)" ::: "memory"); // retires all prior sub-iters
    __builtin_amdgcn_sched_barrier(0);
    __builtin_amdgcn_s_setprio(1);
#pragma unroll
    for (int m=0;m<8;++m)
#pragma unroll
      for (int n=0;n<4;++n)
        acc[m][n] = __builtin_amdgcn_mfma_f32_16x16x32_bf16(a0[m], b0[n], acc[m][n], 0,0,0);
    __builtin_amdgcn_s_setprio(0);
    __builtin_amdgcn_s_barrier();

    // ---- sub-iter t+1 (compute a1/b1) ----
    stageA((t+4)&3, min(t+4, NT-1));
    gloadB(b0, min(t+2, NT-1));
    ldfragA((t+2)&3, a0);
    asm volatile("s_waitcnt vmcnt(6)" ::: "memory");
    __builtin_amdgcn_sched_barrier(0);
    __builtin_amdgcn_s_setprio(1);
#pragma unroll
    for (int m=0;m<8;++m)
#pragma unroll
      for (int n=0;n<4;++n)
        acc[m][n] = __builtin_amdgcn_mfma_f32_16x16x32_bf16(a1[m], b1[n], acc[m][n], 0,0,0);
    __builtin_amdgcn_s_setprio(0);
    __builtin_amdgcn_s_barrier();
  }

  const int crow = brow + wm*128 + hi * 4;
  const int ccol = bcol + wn*64 + fr;
  if constexpr (OM == 2){
    float* C = (float*)Cv + (long)bz * sC;
#pragma unroll
    for (int m=0;m<8;++m)
#pragma unroll
      for (int n=0;n<4;++n){
        f32x4 v = acc[m][n];
        float* cp = C + (long)(crow + m*16) * N + ccol + n*16;
#pragma unroll
        for (int q=0;q<4;++q) cp[(long)q*N] = v[q];
      }
  } else {
    u16* C = (u16*)Cv + (long)bz * sC;
#pragma unroll
    for (int m=0;m<8;++m)
#pragma unroll
      for (int n=0;n<4;++n){
        f32x4 v = acc[m][n];
        u16* cp = C + (long)(crow + m*16) * N + ccol + n*16;
#pragma unroll
        for (int q=0;q<4;++q) cp[(long)q*N] = OM ? f2h(v[q]) : f2bf(v[q]);
      }
  }

  if constexpr (STATS){
    // ---- row partials: max & sumexp over this wave's 64 cols ----
#pragma unroll
    for (int m=0;m<8;++m){
      f32x4 mx = acc[m][0];
#pragma unroll
      for (int n=1;n<4;++n)
#pragma unroll
        for (int q=0;q<4;++q) mx[q] = fmaxf(mx[q], acc[m][n][q]);
#pragma unroll
      for (int off=1; off<16; off<<=1)
#pragma unroll
        for (int q=0;q<4;++q) mx[q] = fmaxf(mx[q], __shfl_xor(mx[q], off));
      f32x4 sm = (f32x4){0.f,0.f,0.f,0.f};
#pragma unroll
      for (int n=0;n<4;++n)
#pragma unroll
        for (int q=0;q<4;++q) sm[q] += __expf(acc[m][n][q] - mx[q]);
#pragma unroll
      for (int off=1; off<16; off<<=1)
#pragma unroll
        for (int q=0;q<4;++q) sm[q] += __shfl_xor(sm[q], off);
      if (fr == 0){
        const int nb = by_*4 + wn;                             // 0..31
        const long rb = ((long)bz*32 + nb)*2048 + brow + wm*128 + m*16 + hi*4;
#pragma unroll
        for (int q=0;q<4;++q){ rpmax[rb+q] = mx[q]; rpsum[rb+q] = sm[q]; }
      }
    }
    // ---- col partials: max & sumexp over this wave's 128 rows ----
#pragma unroll
    for (int n=0;n<4;++n){
      float mx = acc[0][n][0];
#pragma unroll
      for (int m=0;m<8;++m)
#pragma unroll
        for (int q=0;q<4;++q) mx = fmaxf(mx, acc[m][n][q]);
      mx = fmaxf(mx, __shfl_xor(mx, 16));
      mx = fmaxf(mx, __shfl_xor(mx, 32));
      float sm = 0.f;
#pragma unroll
      for (int m=0;m<8;++m)
#pragma unroll
        for (int q=0;q<4;++q) sm += __expf(acc[m][n][q] - mx);
      sm += __shfl_xor(sm, 16);
      sm += __shfl_xor(sm, 32);
      if (hi == 0){
        const int mb = bx_*2 + wm;                             // 0..15
        const long cb = ((long)bz*16 + mb)*2048 + bcol + wn*64 + n*16 + fr;
        cpmax[cb] = mx; cpsum[cb] = sm;
      }
    }
  }
}

// ---- combine split-softmax partials -> exact rmax/rinv (y=0) & cmax/cinv (y=1) ----
__global__ __launch_bounds__(256) void k_combine(
    const float* __restrict__ rpmax, const float* __restrict__ rpsum,
    const float* __restrict__ cpmax, const float* __restrict__ cpsum,
    float* __restrict__ rmax, float* __restrict__ rinv,
    float* __restrict__ cmax, float* __restrict__ cinv)
{
  const long i = (long)blockIdx.x*256 + threadIdx.x;   // 0..16383
  const int b = (int)(i >> 11), r = (int)(i & 2047);
  if (blockIdx.y == 0){
    const float* pm = rpmax + ((long)b*32)*2048 + r;
    const float* ps = rpsum + ((long)b*32)*2048 + r;
    float m = -3.4e38f;
#pragma unroll
    for (int k=0;k<32;++k) m = fmaxf(m, pm[(long)k*2048]);
    float s = 0.f;
#pragma unroll
    for (int k=0;k<32;++k) s += ps[(long)k*2048] * __expf(pm[(long)k*2048] - m);
    rmax[i] = m; rinv[i] = 1.f / s;
  } else {
    const float* pm = cpmax + ((long)b*16)*2048 + r;
    const float* ps = cpsum + ((long)b*16)*2048 + r;
    float m = -3.4e38f;
#pragma unroll
    for (int k=0;k<16;++k) m = fmaxf(m, pm[(long)k*2048]);
    float s = 0.f;
#pragma unroll
    for (int k=0;k<16;++k) s += ps[(long)k*2048] * __expf(pm[(long)k*2048] - m);
    cmax[i] = m; cinv[i] = 1.f / s;
  }
}

// ---- in-place per-batch transform: Wg(fp16 scores) -> P1T (bf16, transposed)
// and (when P2 != nullptr) P2 = row-softmax (bf16, natural layout).
__global__ __launch_bounds__(256) void k_p1t(u16* __restrict__ Wg, u16* __restrict__ P2,
                                             const float* __restrict__ cmax,
                                             const float* __restrict__ cinv,
                                             const float* __restrict__ rmax,
                                             const float* __restrict__ rinv){
  const int ti = blockIdx.x, tj = blockIdx.y;
  if (tj < ti) return;
  const int b = blockIdx.z;
  u16* S = Wg + (long)b * S1_ * S2_;
  const int jl = threadIdx.x & 63, ig = threadIdx.x >> 6;   // ig 0..3
  const int I0 = ti*64, J0 = tj*64;
  const float cmA = cmax[b*S2_ + J0 + jl], ciA = cinv[b*S2_ + J0 + jl];
  const float cmB = cmax[b*S2_ + I0 + jl], ciB = cinv[b*S2_ + I0 + jl];
  float ra[16], rc[16];
#pragma unroll
  for (int q=0;q<16;++q) ra[q] = h2f(S[(long)(I0 + ig*16 + q)*S2_ + J0 + jl]);
#pragma unroll
  for (int q=0;q<16;++q) rc[q] = h2f(S[(long)(J0 + ig*16 + q)*S2_ + I0 + jl]);

  if (P2){
    u16* P2b = P2 + (long)b * S1_ * S2_;
#pragma unroll
    for (int q=0;q<16;++q){
      const int r = I0 + ig*16 + q;
      P2b[(long)r*S2_ + J0 + jl] = f2bf(__expf(ra[q] - rmax[b*S1_+r]) * rinv[b*S1_+r]);
    }
    if (ti != tj){
#pragma unroll
      for (int q=0;q<16;++q){
        const int r = J0 + ig*16 + q;
        P2b[(long)r*S2_ + I0 + jl] = f2bf(__expf(rc[q] - rmax[b*S1_+r]) * rinv[b*S1_+r]);
      }
    }
  }

  float a[16], c[16];
#pragma unroll
  for (int q=0;q<16;++q) a[q] = __expf(ra[q] - cmA) * ciA;
#pragma unroll
  for (int q=0;q<16;++q) c[q] = __expf(rc[q] - cmB) * ciB;
  __syncthreads();
  union { bf16x8 v; uint32_t w4[4]; } o0, o1;
#pragma unroll
  for (int k=0;k<4;++k){ o0.w4[k] = pk2bf(a[2*k], a[2*k+1]); o1.w4[k] = pk2bf(a[8+2*k], a[9+2*k]); }
  *(bf16x8*)(S + (long)(J0+jl)*S2_ + I0 + ig*16)     = o0.v;
  *(bf16x8*)(S + (long)(J0+jl)*S2_ + I0 + ig*16 + 8) = o1.v;
#pragma unroll
  for (int k=0;k<4;++k){ o0.w4[k] = pk2bf(c[2*k], c[2*k+1]); o1.w4[k] = pk2bf(c[8+2*k], c[9+2*k]); }
  *(bf16x8*)(S + (long)(I0+jl)*S2_ + J0 + ig*16)     = o0.v;
  *(bf16x8*)(S + (long)(I0+jl)*S2_ + J0 + ig*16 + 8) = o1.v;
}

// -------- fallback: hidden_2 = rowsoftmax(scores) @ h2t^T (fused A, 128 tile) --------
__global__ __launch_bounds__(256) void k_gemm_h2(
    const u16* __restrict__ Wg, const u16* __restrict__ Bt, float* __restrict__ C,
    const float* __restrict__ rmax, const float* __restrict__ rinv)
{
  const int b = blockIdx.z;
  const u16* A  = Wg + (long)b * S1_ * S2_;
  const u16* Bp = Bt + (long)b * H_ * S2_;
  float* Cp = C + (long)b * S1_ * H_;

  __shared__ u16 As[128*32];
  __shared__ u16 Bs[128*32];
  const int tid = threadIdx.x, lane = tid & 63, w = tid >> 6;
  const int wr = (w >> 1) * 64, wc = (w & 1) * 64;
  const int brow = blockIdx.x * 128, bcol = blockIdx.y * 128;
  f32x4 acc[4][4];
#pragma unroll
  for (int m=0;m<4;++m)
#pragma unroll
    for (int n=0;n<4;++n) acc[m][n] = (f32x4){0.f,0.f,0.f,0.f};

  const int arow = w*16 + (lane >> 2);
  const int scol = (lane & 3) * 8;
  const u16* gA0 = A + (long)(brow + arow) * S2_ + scol;
  const u16* gA1 = gA0 + (long)64 * S2_;
  const float rm0 = rmax[b*S1_ + brow + arow],      ri0 = rinv[b*S1_ + brow + arow];
  const float rm1 = rmax[b*S1_ + brow + arow + 64], ri1 = rinv[b*S1_ + brow + arow + 64];
  u16* wA0 = As + arow*32 + scol;
  u16* wA1 = As + (arow+64)*32 + scol;

  const u16* gb = Bp + (long)(bcol + arow) * S2_ + scol;
  u16* lB0 = Bs + (w*16)*32;  u16* lB1 = Bs + (64 + w*16)*32;

  const int koff = (lane >> 4) * 8;
  const int fr = lane & 15;

  for (int k0 = 0; k0 < S2_; k0 += 32){
    bf16x8 x0 = *(const bf16x8*)(gA0 + k0);
    bf16x8 x1 = *(const bf16x8*)(gA1 + k0);
    async16(lB0, gb);  async16(lB1, gb + (long)64*S2_);
    gb += 32;
    union { bf16x8 v; uint32_t w4[4]; } y0, y1;
#pragma unroll
    for (int k=0;k<4;++k){
      y0.w4[k] = pk2bf(__expf(h2f((u16)x0[2*k])   - rm0) * ri0,
                       __expf(h2f((u16)x0[2*k+1]) - rm0) * ri0);
      y1.w4[k] = pk2bf(__expf(h2f((u16)x1[2*k])   - rm1) * ri1,
                       __expf(h2f((u16)x1[2*k+1]) - rm1) * ri1);
    }
    *(bf16x8*)wA0 = y0.v;
    *(bf16x8*)wA1 = y1.v;
    __syncthreads();
    bf16x8 af[4], bf[4];
#pragma unroll
    for (int m=0;m<4;++m) af[m] = *(const bf16x8*)(As + (wr + m*16 + fr)*32 + koff);
#pragma unroll
    for (int n=0;n<4;++n) bf[n] = *(const bf16x8*)(Bs + (wc + n*16 + fr)*32 + koff);
#pragma unroll
    for (int m=0;m<4;++m)
#pragma unroll
      for (int n=0;n<4;++n)
        acc[m][n] = __builtin_amdgcn_mfma_f32_16x16x32_bf16(af[m], bf[n], acc[m][n], 0,0,0);
    __syncthreads();
  }
  const int crow = brow + wr + (lane >> 4) * 4;
  const int ccol = bcol + wc + fr;
#pragma unroll
  for (int m=0;m<4;++m)
#pragma unroll
    for (int n=0;n<4;++n){
      f32x4 v = acc[m][n];
      float* cp = Cp + (long)(crow + m*16) * H_ + ccol + n*16;
#pragma unroll
      for (int q=0;q<4;++q) cp[(long)q*H_] = v[q];
    }
}

extern "C" void kernel_launch(void* const* d_in, const int* in_sizes, int n_in,
                              void* d_out, int out_size, void* d_ws, size_t ws_size,
                              hipStream_t stream)
{
  const float* h1 = (const float*)d_in[0];   // hidden1 (B,S1,H) fp32
  const float* h2 = (const float*)d_in[1];   // hidden2 (B,S2,H) fp32
  const float* W  = (const float*)d_in[2];   // W (H,H) fp32
  // bias (d_in[3]): uniform shift of scores -> softmax-invariant: unused.
  float* out0 = (float*)d_out;                        // hidden_1 (B,S2,H) fp32
  float* out1 = out0 + (size_t)B_ * S2_ * H_;         // hidden_2 (B,S1,H) fp32

  const long NE = (long)B_ * S1_ * H_;       // 16.78M
  const long NS = (long)B_ * S1_ * S2_;      // 33.55M

  // ws layout — byte-identical to r10-r12 (proven): stats, Wg, h1t, [P2], [h2t].
  char* ws = (char*)d_ws;
  size_t off = 0;
  float* rmax = (float*)(ws + off); off += (size_t)B_*S1_*4;
  float* rinv = (float*)(ws + off); off += (size_t)B_*S1_*4;
  float* cmax = (float*)(ws + off); off += (size_t)B_*S2_*4;
  float* cinv = (float*)(ws + off); off += (size_t)B_*S2_*4;
  u16* Wg  = (u16*)(ws + off);                       // fp16 scores -> P1T in place
  u16* WTb = Wg;                                     // bf16 W^T, dead before Wg written
  off += (size_t)NS*2;
  u16* h1t = (u16*)(ws + off); off += (size_t)NE*2;  // bf16 h1^T [B][H][S1]

  const bool use_p2 = ws_size >= off + (size_t)NS*2;
  u16* P2 = use_p2 ? (u16*)(ws + off) : (u16*)nullptr;
  size_t off2 = off + (use_p2 ? (size_t)NS*2 : 0);
  const bool ws_h2t = ws_size >= off2 + (size_t)NE*2;

  u16* h1b = (u16*)out0;
  u16* h2b = (u16*)out0 + NE;
  u16* h2t = ws_h2t ? (u16*)(ws + off2) : (u16*)out0;
  u16* Qb  = (u16*)out1;
  // split-softmax partials live in out1's dead SECOND half (6 MB of 33.5 MB):
  float* rpmax = (float*)((u16*)out1 + NE);                 // [8][32][2048]
  float* rpsum = rpmax + (size_t)B_*32*2048;
  float* cpmax = rpsum + (size_t)B_*32*2048;                // [8][16][2048]
  float* cpsum = cpmax + (size_t)B_*16*2048;

  k_cvtT2<<<dim3(16,32,8), 256, 0, stream>>>(h1, h1b, h1t, S1_, H_);
  if (ws_h2t){
    k_cvtT2<<<dim3(16,32,8), 256, 0, stream>>>(h2, h2b, h2t, S2_, H_);
  } else {
    k_cvt_bf16<<<dim3(4096), 256, 0, stream>>>(h2, h2b, NE);
  }
  k_tcvt<<<dim3(32,32,1), 256, 0, stream>>>(W, WTb, H_, H_);
  // Q = h1b @ WTb^T  (M=S1,N=H,K=H) -> bf16 (out1 first half)
  k_gemm256<0,false><<<dim3(8, 4, 8), 512, 0, stream>>>(h1b, WTb, Qb, S1_, H_, H_,
        (long)S1_*H_, 0L, (long)S1_*H_, nullptr, nullptr, nullptr, nullptr);
  if (!ws_h2t){
    k_tcvt<<<dim3(32,64,8), 256, 0, stream>>>(h2, h2t, S2_, H_);
  }
  // scores = Qb @ h2b^T -> fp16 Wg; epilogue emits split-softmax partials
  k_gemm256<1,true><<<dim3(8, 8, 8), 512, 0, stream>>>(Qb, h2b, Wg, S1_, S2_, H_,
        (long)S1_*H_, (long)S2_*H_, (long)S1_*S2_, rpmax, rpsum, cpmax, cpsum);
  // combine partials -> exact rmax/rinv (rows) and cmax/cinv (cols)
  k_combine<<<dim3(64, 2), 256, 0, stream>>>(rpmax, rpsum, cpmax, cpsum,
                                             rmax, rinv, cmax, cinv);
  if (use_p2){
    // Wg -> P1T (in place) + P2 (row-softmax); then both output GEMMs are plain bt.
    k_p1t<<<dim3(32,32,8), 256, 0, stream>>>(Wg, P2, cmax, cinv, rmax, rinv);
    // hidden_2 = P2 @ h2t^T -> out1 (overwrites Qb + partials, both dead)
    k_gemm256<2,false><<<dim3(8, 4, 8), 512, 0, stream>>>(P2, h2t, out1, S1_, H_, S2_,
          (long)S1_*S2_, (long)H_*S2_, (long)S1_*H_, nullptr, nullptr, nullptr, nullptr);
  } else {
    // fallback: fused h2 GEMM must read RAW Wg before p1t destroys it
    k_gemm_h2<<<dim3(16, 8, 8), 256, 0, stream>>>(Wg, h2t, out1, rmax, rinv);
    k_p1t<<<dim3(32,32,8), 256, 0, stream>>>(Wg, (u16*)nullptr, cmax, cinv, rmax, rinv);
  }
  // hidden_1 = P1T @ h1t^T -> out0 (M=S2,N=H,K=S1)
  k_gemm256<2,false><<<dim3(8, 4, 8), 512, 0, stream>>>(Wg, h1t, out0, S2_, H_, S1_,
        (long)S1_*S2_, (long)H_*S1_, (long)S2_*H_, nullptr, nullptr, nullptr, nullptr);
}

// Round 15
// 384.872 us; speedup vs baseline: 1.3022x; 1.3022x over previous
//
#include <hip/hip_runtime.h>
#include <stdint.h>

#define B_  8
#define S1_ 2048
#define S2_ 2048
#define H_  1024

typedef __attribute__((ext_vector_type(8))) short bf16x8;
typedef __attribute__((ext_vector_type(4))) float f32x4;
typedef unsigned short u16;

__device__ __forceinline__ u16 f2bf(float f){
  union { float f; uint32_t v; } x; x.f = f;
  uint32_t r = x.v + 0x7fffu + ((x.v >> 16) & 1u);
  return (u16)(r >> 16);
}
__device__ __forceinline__ u16 f2h(float f){
  union { _Float16 h; u16 u; } c; c.h = (_Float16)f; return c.u;
}
__device__ __forceinline__ float h2f(u16 u){
  union { _Float16 h; u16 u; } c; c.u = u; return (float)c.h;
}
// packed f32x2 -> bf16x2 (RNE), 1 VALU op for 2 elements
__device__ __forceinline__ uint32_t pk2bf(float lo, float hi){
  uint32_t r;
  asm("v_cvt_pk_bf16_f32 %0, %1, %2" : "=v"(r) : "v"(lo), "v"(hi));
  return r;
}
__device__ __forceinline__ void async16(void* lds, const void* g){
  __builtin_amdgcn_global_load_lds(
      (const __attribute__((address_space(1))) uint32_t*)g,
      (__attribute__((address_space(3))) uint32_t*)lds, 16, 0, 0);
}

// ---------------- fp32 -> bf16 copy ----------------
__global__ __launch_bounds__(256) void k_cvt_bf16(const float* __restrict__ in,
                                                  u16* __restrict__ out, long n){
  long i = ((long)blockIdx.x * 256 + threadIdx.x) * 8;
  const long stride = (long)gridDim.x * 256 * 8;
  for (; i < n; i += stride){
    float4 a = *(const float4*)(in + i);
    float4 b = *(const float4*)(in + i + 4);
    union { bf16x8 v; uint32_t w[4]; } o;
    o.w[0] = pk2bf(a.x, a.y); o.w[1] = pk2bf(a.z, a.w);
    o.w[2] = pk2bf(b.x, b.y); o.w[3] = pk2bf(b.z, b.w);
    *(bf16x8*)(out + i) = o.v;
  }
}

// ------- batched fp32 [R][C] -> bf16 [C][R] transpose (32x32, for W) -------
__global__ __launch_bounds__(256) void k_tcvt(const float* __restrict__ in,
                                              u16* __restrict__ out, int R, int Cc){
  __shared__ u16 t[32][33];
  in  += (long)blockIdx.z * R * Cc;
  out += (long)blockIdx.z * R * Cc;
  const int x = threadIdx.x & 31, y0 = threadIdx.x >> 5;
  const int bx = blockIdx.x * 32, by = blockIdx.y * 32;
  for (int r = y0; r < 32; r += 8) t[r][x] = f2bf(in[(long)(by + r) * Cc + bx + x]);
  __syncthreads();
  for (int r = y0; r < 32; r += 8) out[(long)(bx + r) * R + by + x] = t[x][r];
}

// ------- batched fp32 [R][C] -> bf16 copy AND bf16 transpose, 64x64 tiles -------
__global__ __launch_bounds__(256) void k_cvtT2(const float* __restrict__ in,
                                               u16* __restrict__ out_n,
                                               u16* __restrict__ out_t, int R, int Cc){
  __shared__ u16 t[64][68];
  in    += (long)blockIdx.z * R * Cc;
  out_n += (long)blockIdx.z * R * Cc;
  out_t += (long)blockIdx.z * R * Cc;
  const int tid = threadIdx.x;
  const int r0 = tid >> 4;            // 0..15
  const int c4 = (tid & 15) * 4;      // 0,4,...,60
  const int bx = blockIdx.x * 64;     // col base
  const int by = blockIdx.y * 64;     // row base
#pragma unroll
  for (int it = 0; it < 4; ++it){
    const int r = it*16 + r0;
    float4 v = *(const float4*)(in + (long)(by + r)*Cc + bx + c4);
    u16 b0 = f2bf(v.x), b1 = f2bf(v.y), b2 = f2bf(v.z), b3 = f2bf(v.w);
    ushort4 o; o.x = b0; o.y = b1; o.z = b2; o.w = b3;
    *(ushort4*)(out_n + (long)(by + r)*Cc + bx + c4) = o;
    t[r][c4] = b0; t[r][c4+1] = b1; t[r][c4+2] = b2; t[r][c4+3] = b3;
  }
  __syncthreads();
#pragma unroll
  for (int it = 0; it < 4; ++it){
    const int c = it*16 + r0;         // input col = output row
    ushort4 o;
    o.x = t[c4  ][c]; o.y = t[c4+1][c]; o.z = t[c4+2][c]; o.w = t[c4+3][c];
    *(ushort4*)(out_t + (long)(bx + c)*R + by + c4) = o;
  }
}

// ======= 256x256-tile pipelined bt-GEMM: C = A @ B^T =======
// r12 core (best measured, 385 us total): BK=32, 8 waves, 4 LDS buffers,
// 3-tile prefetch (counted vmcnt(4)), register fragment double-buffer,
// conflict-free slot swizzle (r9: SQ_LDS_BANK_CONFLICT = 0).
// T1: XCD-aware chunked block swizzle (r12: FETCH 147.5 -> 49.3 MB).
// STATS: scores-GEMM epilogue emits split-softmax partials.
// OM: 0 bf16 C, 1 fp16 C, 2 fp32 C.
template<int OM, bool STATS>
__global__ __launch_bounds__(512) void k_gemm256(
    const u16* __restrict__ A, const u16* __restrict__ Bm, void* __restrict__ Cv,
    int M, int N, int K, long sA, long sB, long sC,
    float* __restrict__ rpmax, float* __restrict__ rpsum,
    float* __restrict__ cpmax, float* __restrict__ cpsum)
{
  // ---- XCD chunked swizzle (bijective; total blocks % 8 == 0 by grid design)
  const int GX = gridDim.x, GY = gridDim.y;
  const long plane = (long)GX * GY;
  const long tot = plane * gridDim.z;
  const long lin = blockIdx.x + (long)GX * (blockIdx.y + (long)GY * blockIdx.z);
  const long chunk = tot >> 3;
  const long swz = (lin & 7) * chunk + (lin >> 3);
  const int bz = (int)(swz / plane);
  const int rr = (int)(swz % plane);
  const int by_ = rr / GX, bx_ = rr % GX;

  A += (long)bz * sA; Bm += (long)bz * sB;
  __shared__ u16 lds[4 * 16384];          // [buf][ A 256x32 | B 256x32 ] = 128 KB
  const int tid = threadIdx.x, lane = tid & 63, w = tid >> 6;
  const int wm = w >> 2, wn = w & 3;      // 2 x 4 wave grid
  const int brow = bx_ * 256, bcol = by_ * 256;

  f32x4 acc[8][4];
#pragma unroll
  for (int m=0;m<8;++m)
#pragma unroll
    for (int n=0;n<4;++n) acc[m][n] = (f32x4){0.f,0.f,0.f,0.f};

  const int fr = lane & 15;
  const int g8s = ((lane >> 4) ^ ((lane >> 1) & 3)) * 8;   // conflict-free read slot

  const int cc0 = w*128 + lane;
  const int cc1 = w*128 + 64 + lane;
  const int sl0 = (cc0 & 3) ^ ((cc0 >> 3) & 3);
  const int sl1 = (cc1 & 3) ^ ((cc1 >> 3) & 3);
  const u16* gA0 = A  + (long)(brow + (cc0 >> 2)) * K + sl0*8;
  const u16* gA1 = A  + (long)(brow + (cc1 >> 2)) * K + sl1*8;
  const u16* gB0 = Bm + (long)(bcol + (cc0 >> 2)) * K + sl0*8;
  const u16* gB1 = Bm + (long)(bcol + (cc1 >> 2)) * K + sl1*8;
  const int ldA0 = (w*128)*8, ldA1 = (w*128 + 64)*8;

  auto stage = [&](int buf, int t){
    u16* base = lds + buf*16384;
    async16(base + ldA0,        gA0 + t*32);
    async16(base + ldA1,        gA1 + t*32);
    async16(base + 8192 + ldA0, gB0 + t*32);
    async16(base + 8192 + ldA1, gB1 + t*32);
  };
  auto ldfrag = [&](int buf, bf16x8* a, bf16x8* b){
    const u16* At = lds + buf*16384;
    const u16* Bt = At + 8192;
#pragma unroll
    for (int n=0;n<4;++n) b[n] = *(const bf16x8*)(Bt + (wn*64 + n*16 + fr)*32 + g8s);
#pragma unroll
    for (int m=0;m<8;++m) a[m] = *(const bf16x8*)(At + (wm*128 + m*16 + fr)*32 + g8s);
  };

  const int NT = K >> 5;                   // even (K multiple of 64)
  stage(0,0); stage(1,1); stage(2,2);
  asm volatile("s_waitcnt vmcnt(4)" ::: "memory");   // tiles 0,1 landed
  __builtin_amdgcn_s_barrier();

  bf16x8 a0[8], b0[4], a1[8], b1[4];
  ldfrag(0, a0, b0);

  for (int t = 0; t < NT; t += 2){
    if (t + 3 < NT) stage((t+3)&3, t+3);
    ldfrag((t+1)&3, a1, b1);
    __builtin_amdgcn_sched_barrier(0);
    __builtin_amdgcn_s_setprio(1);
#pragma unroll
    for (int m=0;m<8;++m)
#pragma unroll
      for (int n=0;n<4;++n)
        acc[m][n] = __builtin_amdgcn_mfma_f32_16x16x32_bf16(a0[m], b0[n], acc[m][n], 0,0,0);
    __builtin_amdgcn_s_setprio(0);
    asm volatile("s_waitcnt vmcnt(4)" ::: "memory");
    __builtin_amdgcn_s_barrier();

    if (t + 4 < NT) stage((t+4)&3, t+4);
    if (t + 2 < NT) ldfrag((t+2)&3, a0, b0);
    __builtin_amdgcn_sched_barrier(0);
    __builtin_amdgcn_s_setprio(1);
#pragma unroll
    for (int m=0;m<8;++m)
#pragma unroll
      for (int n=0;n<4;++n)
        acc[m][n] = __builtin_amdgcn_mfma_f32_16x16x32_bf16(a1[m], b1[n], acc[m][n], 0,0,0);
    __builtin_amdgcn_s_setprio(0);
    if (t + 2 < NT){
      asm volatile("s_waitcnt vmcnt(4)" ::: "memory");
      __builtin_amdgcn_s_barrier();
    }
  }

  const int crow = brow + wm*128 + (lane >> 4) * 4;
  const int ccol = bcol + wn*64 + fr;
  if constexpr (OM == 2){
    float* C = (float*)Cv + (long)bz * sC;
#pragma unroll
    for (int m=0;m<8;++m)
#pragma unroll
      for (int n=0;n<4;++n){
        f32x4 v = acc[m][n];
        float* cp = C + (long)(crow + m*16) * N + ccol + n*16;
#pragma unroll
        for (int q=0;q<4;++q) cp[(long)q*N] = v[q];
      }
  } else {
    u16* C = (u16*)Cv + (long)bz * sC;
#pragma unroll
    for (int m=0;m<8;++m)
#pragma unroll
      for (int n=0;n<4;++n){
        f32x4 v = acc[m][n];
        u16* cp = C + (long)(crow + m*16) * N + ccol + n*16;
#pragma unroll
        for (int q=0;q<4;++q) cp[(long)q*N] = OM ? f2h(v[q]) : f2bf(v[q]);
      }
  }

  if constexpr (STATS){
    const int hi = lane >> 4;
    // ---- row partials: max & sumexp over this wave's 64 cols ----
#pragma unroll
    for (int m=0;m<8;++m){
      f32x4 mx = acc[m][0];
#pragma unroll
      for (int n=1;n<4;++n)
#pragma unroll
        for (int q=0;q<4;++q) mx[q] = fmaxf(mx[q], acc[m][n][q]);
#pragma unroll
      for (int off=1; off<16; off<<=1)
#pragma unroll
        for (int q=0;q<4;++q) mx[q] = fmaxf(mx[q], __shfl_xor(mx[q], off));
      f32x4 sm = (f32x4){0.f,0.f,0.f,0.f};
#pragma unroll
      for (int n=0;n<4;++n)
#pragma unroll
        for (int q=0;q<4;++q) sm[q] += __expf(acc[m][n][q] - mx[q]);
#pragma unroll
      for (int off=1; off<16; off<<=1)
#pragma unroll
        for (int q=0;q<4;++q) sm[q] += __shfl_xor(sm[q], off);
      if (fr == 0){
        const int nb = by_*4 + wn;                             // 0..31
        const long rb = ((long)bz*32 + nb)*2048 + brow + wm*128 + m*16 + hi*4;
#pragma unroll
        for (int q=0;q<4;++q){ rpmax[rb+q] = mx[q]; rpsum[rb+q] = sm[q]; }
      }
    }
    // ---- col partials: max & sumexp over this wave's 128 rows ----
#pragma unroll
    for (int n=0;n<4;++n){
      float mx = acc[0][n][0];
#pragma unroll
      for (int m=0;m<8;++m)
#pragma unroll
        for (int q=0;q<4;++q) mx = fmaxf(mx, acc[m][n][q]);
      mx = fmaxf(mx, __shfl_xor(mx, 16));
      mx = fmaxf(mx, __shfl_xor(mx, 32));
      float sm = 0.f;
#pragma unroll
      for (int m=0;m<8;++m)
#pragma unroll
        for (int q=0;q<4;++q) sm += __expf(acc[m][n][q] - mx);
      sm += __shfl_xor(sm, 16);
      sm += __shfl_xor(sm, 32);
      if (hi == 0){
        const int mb = bx_*2 + wm;                             // 0..15
        const long cb = ((long)bz*16 + mb)*2048 + bcol + wn*64 + n*16 + fr;
        cpmax[cb] = mx; cpsum[cb] = sm;
      }
    }
  }
}

// ---- combine split-softmax partials -> exact rmax/rinv (y=0) & cmax/cinv (y=1) ----
__global__ __launch_bounds__(256) void k_combine(
    const float* __restrict__ rpmax, const float* __restrict__ rpsum,
    const float* __restrict__ cpmax, const float* __restrict__ cpsum,
    float* __restrict__ rmax, float* __restrict__ rinv,
    float* __restrict__ cmax, float* __restrict__ cinv)
{
  const long i = (long)blockIdx.x*256 + threadIdx.x;   // 0..16383
  const int b = (int)(i >> 11), r = (int)(i & 2047);
  if (blockIdx.y == 0){
    const float* pm = rpmax + ((long)b*32)*2048 + r;
    const float* ps = rpsum + ((long)b*32)*2048 + r;
    float m = -3.4e38f;
#pragma unroll
    for (int k=0;k<32;++k) m = fmaxf(m, pm[(long)k*2048]);
    float s = 0.f;
#pragma unroll
    for (int k=0;k<32;++k) s += ps[(long)k*2048] * __expf(pm[(long)k*2048] - m);
    rmax[i] = m; rinv[i] = 1.f / s;
  } else {
    const float* pm = cpmax + ((long)b*16)*2048 + r;
    const float* ps = cpsum + ((long)b*16)*2048 + r;
    float m = -3.4e38f;
#pragma unroll
    for (int k=0;k<16;++k) m = fmaxf(m, pm[(long)k*2048]);
    float s = 0.f;
#pragma unroll
    for (int k=0;k<16;++k) s += ps[(long)k*2048] * __expf(pm[(long)k*2048] - m);
    cmax[i] = m; cinv[i] = 1.f / s;
  }
}

// ---- in-place per-batch transform: Wg(fp16 scores) -> P1T (bf16, transposed)
// and (when P2 != nullptr) P2 = row-softmax (bf16, natural layout).
__global__ __launch_bounds__(256) void k_p1t(u16* __restrict__ Wg, u16* __restrict__ P2,
                                             const float* __restrict__ cmax,
                                             const float* __restrict__ cinv,
                                             const float* __restrict__ rmax,
                                             const float* __restrict__ rinv){
  const int ti = blockIdx.x, tj = blockIdx.y;
  if (tj < ti) return;
  const int b = blockIdx.z;
  u16* S = Wg + (long)b * S1_ * S2_;
  const int jl = threadIdx.x & 63, ig = threadIdx.x >> 6;   // ig 0..3
  const int I0 = ti*64, J0 = tj*64;
  const float cmA = cmax[b*S2_ + J0 + jl], ciA = cinv[b*S2_ + J0 + jl];
  const float cmB = cmax[b*S2_ + I0 + jl], ciB = cinv[b*S2_ + I0 + jl];
  float ra[16], rc[16];
#pragma unroll
  for (int q=0;q<16;++q) ra[q] = h2f(S[(long)(I0 + ig*16 + q)*S2_ + J0 + jl]);
#pragma unroll
  for (int q=0;q<16;++q) rc[q] = h2f(S[(long)(J0 + ig*16 + q)*S2_ + I0 + jl]);

  if (P2){
    u16* P2b = P2 + (long)b * S1_ * S2_;
#pragma unroll
    for (int q=0;q<16;++q){
      const int r = I0 + ig*16 + q;
      P2b[(long)r*S2_ + J0 + jl] = f2bf(__expf(ra[q] - rmax[b*S1_+r]) * rinv[b*S1_+r]);
    }
    if (ti != tj){
#pragma unroll
      for (int q=0;q<16;++q){
        const int r = J0 + ig*16 + q;
        P2b[(long)r*S2_ + I0 + jl] = f2bf(__expf(rc[q] - rmax[b*S1_+r]) * rinv[b*S1_+r]);
      }
    }
  }

  float a[16], c[16];
#pragma unroll
  for (int q=0;q<16;++q) a[q] = __expf(ra[q] - cmA) * ciA;
#pragma unroll
  for (int q=0;q<16;++q) c[q] = __expf(rc[q] - cmB) * ciB;
  __syncthreads();
  union { bf16x8 v; uint32_t w4[4]; } o0, o1;
#pragma unroll
  for (int k=0;k<4;++k){ o0.w4[k] = pk2bf(a[2*k], a[2*k+1]); o1.w4[k] = pk2bf(a[8+2*k], a[9+2*k]); }
  *(bf16x8*)(S + (long)(J0+jl)*S2_ + I0 + ig*16)     = o0.v;
  *(bf16x8*)(S + (long)(J0+jl)*S2_ + I0 + ig*16 + 8) = o1.v;
#pragma unroll
  for (int k=0;k<4;++k){ o0.w4[k] = pk2bf(c[2*k], c[2*k+1]); o1.w4[k] = pk2bf(c[8+2*k], c[9+2*k]); }
  *(bf16x8*)(S + (long)(I0+jl)*S2_ + J0 + ig*16)     = o0.v;
  *(bf16x8*)(S + (long)(I0+jl)*S2_ + J0 + ig*16 + 8) = o1.v;
}

// -------- fallback: hidden_2 = rowsoftmax(scores) @ h2t^T (fused A, 128 tile) --------
__global__ __launch_bounds__(256) void k_gemm_h2(
    const u16* __restrict__ Wg, const u16* __restrict__ Bt, float* __restrict__ C,
    const float* __restrict__ rmax, const float* __restrict__ rinv)
{
  const int b = blockIdx.z;
  const u16* A  = Wg + (long)b * S1_ * S2_;
  const u16* Bp = Bt + (long)b * H_ * S2_;
  float* Cp = C + (long)b * S1_ * H_;

  __shared__ u16 As[128*32];
  __shared__ u16 Bs[128*32];
  const int tid = threadIdx.x, lane = tid & 63, w = tid >> 6;
  const int wr = (w >> 1) * 64, wc = (w & 1) * 64;
  const int brow = blockIdx.x * 128, bcol = blockIdx.y * 128;
  f32x4 acc[4][4];
#pragma unroll
  for (int m=0;m<4;++m)
#pragma unroll
    for (int n=0;n<4;++n) acc[m][n] = (f32x4){0.f,0.f,0.f,0.f};

  const int arow = w*16 + (lane >> 2);
  const int scol = (lane & 3) * 8;
  const u16* gA0 = A + (long)(brow + arow) * S2_ + scol;
  const u16* gA1 = gA0 + (long)64 * S2_;
  const float rm0 = rmax[b*S1_ + brow + arow],      ri0 = rinv[b*S1_ + brow + arow];
  const float rm1 = rmax[b*S1_ + brow + arow + 64], ri1 = rinv[b*S1_ + brow + arow + 64];
  u16* wA0 = As + arow*32 + scol;
  u16* wA1 = As + (arow+64)*32 + scol;

  const u16* gb = Bp + (long)(bcol + arow) * S2_ + scol;
  u16* lB0 = Bs + (w*16)*32;  u16* lB1 = Bs + (64 + w*16)*32;

  const int koff = (lane >> 4) * 8;
  const int fr = lane & 15;

  for (int k0 = 0; k0 < S2_; k0 += 32){
    bf16x8 x0 = *(const bf16x8*)(gA0 + k0);
    bf16x8 x1 = *(const bf16x8*)(gA1 + k0);
    async16(lB0, gb);  async16(lB1, gb + (long)64*S2_);
    gb += 32;
    union { bf16x8 v; uint32_t w4[4]; } y0, y1;
#pragma unroll
    for (int k=0;k<4;++k){
      y0.w4[k] = pk2bf(__expf(h2f((u16)x0[2*k])   - rm0) * ri0,
                       __expf(h2f((u16)x0[2*k+1]) - rm0) * ri0);
      y1.w4[k] = pk2bf(__expf(h2f((u16)x1[2*k])   - rm1) * ri1,
                       __expf(h2f((u16)x1[2*k+1]) - rm1) * ri1);
    }
    *(bf16x8*)wA0 = y0.v;
    *(bf16x8*)wA1 = y1.v;
    __syncthreads();
    bf16x8 af[4], bf[4];
#pragma unroll
    for (int m=0;m<4;++m) af[m] = *(const bf16x8*)(As + (wr + m*16 + fr)*32 + koff);
#pragma unroll
    for (int n=0;n<4;++n) bf[n] = *(const bf16x8*)(Bs + (wc + n*16 + fr)*32 + koff);
#pragma unroll
    for (int m=0;m<4;++m)
#pragma unroll
      for (int n=0;n<4;++n)
        acc[m][n] = __builtin_amdgcn_mfma_f32_16x16x32_bf16(af[m], bf[n], acc[m][n], 0,0,0);
    __syncthreads();
  }
  const int crow = brow + wr + (lane >> 4) * 4;
  const int ccol = bcol + wc + fr;
#pragma unroll
  for (int m=0;m<4;++m)
#pragma unroll
    for (int n=0;n<4;++n){
      f32x4 v = acc[m][n];
      float* cp = Cp + (long)(crow + m*16) * H_ + ccol + n*16;
#pragma unroll
      for (int q=0;q<4;++q) cp[(long)q*H_] = v[q];
    }
}

extern "C" void kernel_launch(void* const* d_in, const int* in_sizes, int n_in,
                              void* d_out, int out_size, void* d_ws, size_t ws_size,
                              hipStream_t stream)
{
  const float* h1 = (const float*)d_in[0];   // hidden1 (B,S1,H) fp32
  const float* h2 = (const float*)d_in[1];   // hidden2 (B,S2,H) fp32
  const float* W  = (const float*)d_in[2];   // W (H,H) fp32
  // bias (d_in[3]): uniform shift of scores -> softmax-invariant: unused.
  float* out0 = (float*)d_out;                        // hidden_1 (B,S2,H) fp32
  float* out1 = out0 + (size_t)B_ * S2_ * H_;         // hidden_2 (B,S1,H) fp32

  const long NE = (long)B_ * S1_ * H_;       // 16.78M
  const long NS = (long)B_ * S1_ * S2_;      // 33.55M

  // ws layout — byte-identical to r10-r12 (proven): stats, Wg, h1t, [P2], [h2t].
  char* ws = (char*)d_ws;
  size_t off = 0;
  float* rmax = (float*)(ws + off); off += (size_t)B_*S1_*4;
  float* rinv = (float*)(ws + off); off += (size_t)B_*S1_*4;
  float* cmax = (float*)(ws + off); off += (size_t)B_*S2_*4;
  float* cinv = (float*)(ws + off); off += (size_t)B_*S2_*4;
  u16* Wg  = (u16*)(ws + off);                       // fp16 scores -> P1T in place
  u16* WTb = Wg;                                     // bf16 W^T, dead before Wg written
  off += (size_t)NS*2;
  u16* h1t = (u16*)(ws + off); off += (size_t)NE*2;  // bf16 h1^T [B][H][S1]

  const bool use_p2 = ws_size >= off + (size_t)NS*2;
  u16* P2 = use_p2 ? (u16*)(ws + off) : (u16*)nullptr;
  size_t off2 = off + (use_p2 ? (size_t)NS*2 : 0);
  const bool ws_h2t = ws_size >= off2 + (size_t)NE*2;

  u16* h1b = (u16*)out0;
  u16* h2b = (u16*)out0 + NE;
  u16* h2t = ws_h2t ? (u16*)(ws + off2) : (u16*)out0;
  u16* Qb  = (u16*)out1;
  // split-softmax partials live in out1's dead SECOND half (6 MB of 33.5 MB):
  float* rpmax = (float*)((u16*)out1 + NE);                 // [8][32][2048]
  float* rpsum = rpmax + (size_t)B_*32*2048;
  float* cpmax = rpsum + (size_t)B_*32*2048;                // [8][16][2048]
  float* cpsum = cpmax + (size_t)B_*16*2048;

  k_cvtT2<<<dim3(16,32,8), 256, 0, stream>>>(h1, h1b, h1t, S1_, H_);
  if (ws_h2t){
    k_cvtT2<<<dim3(16,32,8), 256, 0, stream>>>(h2, h2b, h2t, S2_, H_);
  } else {
    k_cvt_bf16<<<dim3(4096), 256, 0, stream>>>(h2, h2b, NE);
  }
  k_tcvt<<<dim3(32,32,1), 256, 0, stream>>>(W, WTb, H_, H_);
  // Q = h1b @ WTb^T  (M=S1,N=H,K=H) -> bf16 (out1 first half)
  k_gemm256<0,false><<<dim3(8, 4, 8), 512, 0, stream>>>(h1b, WTb, Qb, S1_, H_, H_,
        (long)S1_*H_, 0L, (long)S1_*H_, nullptr, nullptr, nullptr, nullptr);
  if (!ws_h2t){
    k_tcvt<<<dim3(32,64,8), 256, 0, stream>>>(h2, h2t, S2_, H_);
  }
  // scores = Qb @ h2b^T -> fp16 Wg; epilogue emits split-softmax partials
  k_gemm256<1,true><<<dim3(8, 8, 8), 512, 0, stream>>>(Qb, h2b, Wg, S1_, S2_, H_,
        (long)S1_*H_, (long)S2_*H_, (long)S1_*S2_, rpmax, rpsum, cpmax, cpsum);
  // combine partials -> exact rmax/rinv (rows) and cmax/cinv (cols)
  k_combine<<<dim3(64, 2), 256, 0, stream>>>(rpmax, rpsum, cpmax, cpsum,
                                             rmax, rinv, cmax, cinv);
  if (use_p2){
    // Wg -> P1T (in place) + P2 (row-softmax); then both output GEMMs are plain bt.
    k_p1t<<<dim3(32,32,8), 256, 0, stream>>>(Wg, P2, cmax, cinv, rmax, rinv);
    // hidden_2 = P2 @ h2t^T -> out1 (overwrites Qb + partials, both dead)
    k_gemm256<2,false><<<dim3(8, 4, 8), 512, 0, stream>>>(P2, h2t, out1, S1_, H_, S2_,
          (long)S1_*S2_, (long)H_*S2_, (long)S1_*H_, nullptr, nullptr, nullptr, nullptr);
  } else {
    // fallback: fused h2 GEMM must read RAW Wg before p1t destroys it
    k_gemm_h2<<<dim3(16, 8, 8), 256, 0, stream>>>(Wg, h2t, out1, rmax, rinv);
    k_p1t<<<dim3(32,32,8), 256, 0, stream>>>(Wg, (u16*)nullptr, cmax, cinv, rmax, rinv);
  }
  // hidden_1 = P1T @ h1t^T -> out0 (M=S2,N=H,K=S1)
  k_gemm256<2,false><<<dim3(8, 4, 8), 512, 0, stream>>>(Wg, h1t, out0, S2_, H_, S1_,
        (long)S1_*S2_, (long)H_*S1_, (long)S2_*H_, nullptr, nullptr, nullptr, nullptr);
}

// Round 16
// 357.396 us; speedup vs baseline: 1.4023x; 1.0769x over previous
//
#include <hip/hip_runtime.h>
#include <stdint.h>

#define B_  8
#define S1_ 2048
#define S2_ 2048
#define H_  1024

typedef __attribute__((ext_vector_type(8))) short bf16x8;
typedef __attribute__((ext_vector_type(4))) float f32x4;
typedef unsigned short u16;

__device__ __forceinline__ u16 f2bf(float f){
  union { float f; uint32_t v; } x; x.f = f;
  uint32_t r = x.v + 0x7fffu + ((x.v >> 16) & 1u);
  return (u16)(r >> 16);
}
__device__ __forceinline__ u16 f2h(float f){
  union { _Float16 h; u16 u; } c; c.h = (_Float16)f; return c.u;
}
__device__ __forceinline__ float h2f(u16 u){
  union { _Float16 h; u16 u; } c; c.u = u; return (float)c.h;
}
// packed f32x2 -> bf16x2 (RNE), 1 VALU op for 2 elements
__device__ __forceinline__ uint32_t pk2bf(float lo, float hi){
  uint32_t r;
  asm("v_cvt_pk_bf16_f32 %0, %1, %2" : "=v"(r) : "v"(lo), "v"(hi));
  return r;
}
__device__ __forceinline__ void async16(void* lds, const void* g){
  __builtin_amdgcn_global_load_lds(
      (const __attribute__((address_space(1))) uint32_t*)g,
      (__attribute__((address_space(3))) uint32_t*)lds, 16, 0, 0);
}

// ---------------- fp32 -> bf16 copy ----------------
__global__ __launch_bounds__(256) void k_cvt_bf16(const float* __restrict__ in,
                                                  u16* __restrict__ out, long n){
  long i = ((long)blockIdx.x * 256 + threadIdx.x) * 8;
  const long stride = (long)gridDim.x * 256 * 8;
  for (; i < n; i += stride){
    float4 a = *(const float4*)(in + i);
    float4 b = *(const float4*)(in + i + 4);
    union { bf16x8 v; uint32_t w[4]; } o;
    o.w[0] = pk2bf(a.x, a.y); o.w[1] = pk2bf(a.z, a.w);
    o.w[2] = pk2bf(b.x, b.y); o.w[3] = pk2bf(b.z, b.w);
    *(bf16x8*)(out + i) = o.v;
  }
}

// ------- batched fp32 [R][C] -> bf16 [C][R] transpose (32x32, for W) -------
__global__ __launch_bounds__(256) void k_tcvt(const float* __restrict__ in,
                                              u16* __restrict__ out, int R, int Cc){
  __shared__ u16 t[32][33];
  in  += (long)blockIdx.z * R * Cc;
  out += (long)blockIdx.z * R * Cc;
  const int x = threadIdx.x & 31, y0 = threadIdx.x >> 5;
  const int bx = blockIdx.x * 32, by = blockIdx.y * 32;
  for (int r = y0; r < 32; r += 8) t[r][x] = f2bf(in[(long)(by + r) * Cc + bx + x]);
  __syncthreads();
  for (int r = y0; r < 32; r += 8) out[(long)(bx + r) * R + by + x] = t[x][r];
}

// ------- batched fp32 [R][C] -> bf16 copy AND bf16 transpose, 64x64 tiles -------
__global__ __launch_bounds__(256) void k_cvtT2(const float* __restrict__ in,
                                               u16* __restrict__ out_n,
                                               u16* __restrict__ out_t, int R, int Cc){
  __shared__ u16 t[64][68];
  in    += (long)blockIdx.z * R * Cc;
  out_n += (long)blockIdx.z * R * Cc;
  out_t += (long)blockIdx.z * R * Cc;
  const int tid = threadIdx.x;
  const int r0 = tid >> 4;            // 0..15
  const int c4 = (tid & 15) * 4;      // 0,4,...,60
  const int bx = blockIdx.x * 64;     // col base
  const int by = blockIdx.y * 64;     // row base
#pragma unroll
  for (int it = 0; it < 4; ++it){
    const int r = it*16 + r0;
    float4 v = *(const float4*)(in + (long)(by + r)*Cc + bx + c4);
    u16 b0 = f2bf(v.x), b1 = f2bf(v.y), b2 = f2bf(v.z), b3 = f2bf(v.w);
    ushort4 o; o.x = b0; o.y = b1; o.z = b2; o.w = b3;
    *(ushort4*)(out_n + (long)(by + r)*Cc + bx + c4) = o;
    t[r][c4] = b0; t[r][c4+1] = b1; t[r][c4+2] = b2; t[r][c4+3] = b3;
  }
  __syncthreads();
#pragma unroll
  for (int it = 0; it < 4; ++it){
    const int c = it*16 + r0;         // input col = output row
    ushort4 o;
    o.x = t[c4  ][c]; o.y = t[c4+1][c]; o.z = t[c4+2][c]; o.w = t[c4+3][c];
    *(ushort4*)(out_t + (long)(bx + c)*R + by + c4) = o;
  }
}

// ------- merged dual-tensor cvtT2: z<8 -> tensor 1 (batch z), z>=8 -> tensor 2 -------
__global__ __launch_bounds__(256) void k_cvtT2m(
    const float* __restrict__ in1, u16* __restrict__ n1, u16* __restrict__ t1,
    const float* __restrict__ in2, u16* __restrict__ n2, u16* __restrict__ t2,
    int R, int Cc){
  __shared__ u16 t[64][68];
  const int zb = blockIdx.z & 7;
  const bool second = blockIdx.z >= 8;
  const float* in = (second ? in2 : in1) + (long)zb * R * Cc;
  u16* out_n = (second ? n2 : n1) + (long)zb * R * Cc;
  u16* out_t = (second ? t2 : t1) + (long)zb * R * Cc;
  const int tid = threadIdx.x;
  const int r0 = tid >> 4;
  const int c4 = (tid & 15) * 4;
  const int bx = blockIdx.x * 64;
  const int by = blockIdx.y * 64;
#pragma unroll
  for (int it = 0; it < 4; ++it){
    const int r = it*16 + r0;
    float4 v = *(const float4*)(in + (long)(by + r)*Cc + bx + c4);
    u16 b0 = f2bf(v.x), b1 = f2bf(v.y), b2 = f2bf(v.z), b3 = f2bf(v.w);
    ushort4 o; o.x = b0; o.y = b1; o.z = b2; o.w = b3;
    *(ushort4*)(out_n + (long)(by + r)*Cc + bx + c4) = o;
    t[r][c4] = b0; t[r][c4+1] = b1; t[r][c4+2] = b2; t[r][c4+3] = b3;
  }
  __syncthreads();
#pragma unroll
  for (int it = 0; it < 4; ++it){
    const int c = it*16 + r0;
    ushort4 o;
    o.x = t[c4  ][c]; o.y = t[c4+1][c]; o.z = t[c4+2][c]; o.w = t[c4+3][c];
    *(ushort4*)(out_t + (long)(bx + c)*R + by + c4) = o;
  }
}

// ======= 256x256-tile pipelined bt-GEMM: C = A @ B^T =======
// r12 core (best measured): BK=32, 8 waves, 4 LDS buffers, 3-tile prefetch
// (counted vmcnt(4)), register fragment double-buffer, conflict-free slot
// swizzle (r9: SQ_LDS_BANK_CONFLICT = 0).
// T1: XCD-aware chunked block swizzle (r12: FETCH 147.5 -> 49.3 MB).
// STATS: scores-GEMM epilogue emits split-softmax partials.
// OM: 0 bf16 C, 1 fp16 C, 2 fp32 C.
template<int OM, bool STATS>
__global__ __launch_bounds__(512) void k_gemm256(
    const u16* __restrict__ A, const u16* __restrict__ Bm, void* __restrict__ Cv,
    int M, int N, int K, long sA, long sB, long sC,
    float* __restrict__ rpmax, float* __restrict__ rpsum,
    float* __restrict__ cpmax, float* __restrict__ cpsum)
{
  // ---- XCD chunked swizzle (bijective; total blocks % 8 == 0 by grid design)
  const int GX = gridDim.x, GY = gridDim.y;
  const long plane = (long)GX * GY;
  const long tot = plane * gridDim.z;
  const long lin = blockIdx.x + (long)GX * (blockIdx.y + (long)GY * blockIdx.z);
  const long chunk = tot >> 3;
  const long swz = (lin & 7) * chunk + (lin >> 3);
  const int bz = (int)(swz / plane);
  const int rr = (int)(swz % plane);
  const int by_ = rr / GX, bx_ = rr % GX;

  A += (long)bz * sA; Bm += (long)bz * sB;
  __shared__ u16 lds[4 * 16384];          // [buf][ A 256x32 | B 256x32 ] = 128 KB
  const int tid = threadIdx.x, lane = tid & 63, w = tid >> 6;
  const int wm = w >> 2, wn = w & 3;      // 2 x 4 wave grid
  const int brow = bx_ * 256, bcol = by_ * 256;

  f32x4 acc[8][4];
#pragma unroll
  for (int m=0;m<8;++m)
#pragma unroll
    for (int n=0;n<4;++n) acc[m][n] = (f32x4){0.f,0.f,0.f,0.f};

  const int fr = lane & 15;
  const int g8s = ((lane >> 4) ^ ((lane >> 1) & 3)) * 8;   // conflict-free read slot

  const int cc0 = w*128 + lane;
  const int cc1 = w*128 + 64 + lane;
  const int sl0 = (cc0 & 3) ^ ((cc0 >> 3) & 3);
  const int sl1 = (cc1 & 3) ^ ((cc1 >> 3) & 3);
  const u16* gA0 = A  + (long)(brow + (cc0 >> 2)) * K + sl0*8;
  const u16* gA1 = A  + (long)(brow + (cc1 >> 2)) * K + sl1*8;
  const u16* gB0 = Bm + (long)(bcol + (cc0 >> 2)) * K + sl0*8;
  const u16* gB1 = Bm + (long)(bcol + (cc1 >> 2)) * K + sl1*8;
  const int ldA0 = (w*128)*8, ldA1 = (w*128 + 64)*8;

  auto stage = [&](int buf, int t){
    u16* base = lds + buf*16384;
    async16(base + ldA0,        gA0 + t*32);
    async16(base + ldA1,        gA1 + t*32);
    async16(base + 8192 + ldA0, gB0 + t*32);
    async16(base + 8192 + ldA1, gB1 + t*32);
  };
  auto ldfrag = [&](int buf, bf16x8* a, bf16x8* b){
    const u16* At = lds + buf*16384;
    const u16* Bt = At + 8192;
#pragma unroll
    for (int n=0;n<4;++n) b[n] = *(const bf16x8*)(Bt + (wn*64 + n*16 + fr)*32 + g8s);
#pragma unroll
    for (int m=0;m<8;++m) a[m] = *(const bf16x8*)(At + (wm*128 + m*16 + fr)*32 + g8s);
  };

  const int NT = K >> 5;                   // even (K multiple of 64)
  stage(0,0); stage(1,1); stage(2,2);
  asm volatile("s_waitcnt vmcnt(4)" ::: "memory");   // tiles 0,1 landed
  __builtin_amdgcn_s_barrier();

  bf16x8 a0[8], b0[4], a1[8], b1[4];
  ldfrag(0, a0, b0);

  for (int t = 0; t < NT; t += 2){
    if (t + 3 < NT) stage((t+3)&3, t+3);
    ldfrag((t+1)&3, a1, b1);
    __builtin_amdgcn_sched_barrier(0);
    __builtin_amdgcn_s_setprio(1);
#pragma unroll
    for (int m=0;m<8;++m)
#pragma unroll
      for (int n=0;n<4;++n)
        acc[m][n] = __builtin_amdgcn_mfma_f32_16x16x32_bf16(a0[m], b0[n], acc[m][n], 0,0,0);
    __builtin_amdgcn_s_setprio(0);
    asm volatile("s_waitcnt vmcnt(4)" ::: "memory");
    __builtin_amdgcn_s_barrier();

    if (t + 4 < NT) stage((t+4)&3, t+4);
    if (t + 2 < NT) ldfrag((t+2)&3, a0, b0);
    __builtin_amdgcn_sched_barrier(0);
    __builtin_amdgcn_s_setprio(1);
#pragma unroll
    for (int m=0;m<8;++m)
#pragma unroll
      for (int n=0;n<4;++n)
        acc[m][n] = __builtin_amdgcn_mfma_f32_16x16x32_bf16(a1[m], b1[n], acc[m][n], 0,0,0);
    __builtin_amdgcn_s_setprio(0);
    if (t + 2 < NT){
      asm volatile("s_waitcnt vmcnt(4)" ::: "memory");
      __builtin_amdgcn_s_barrier();
    }
  }

  const int crow = brow + wm*128 + (lane >> 4) * 4;
  const int ccol = bcol + wn*64 + fr;
  if constexpr (OM == 2){
    float* C = (float*)Cv + (long)bz * sC;
#pragma unroll
    for (int m=0;m<8;++m)
#pragma unroll
      for (int n=0;n<4;++n){
        f32x4 v = acc[m][n];
        float* cp = C + (long)(crow + m*16) * N + ccol + n*16;
#pragma unroll
        for (int q=0;q<4;++q) cp[(long)q*N] = v[q];
      }
  } else {
    u16* C = (u16*)Cv + (long)bz * sC;
#pragma unroll
    for (int m=0;m<8;++m)
#pragma unroll
      for (int n=0;n<4;++n){
        f32x4 v = acc[m][n];
        u16* cp = C + (long)(crow + m*16) * N + ccol + n*16;
#pragma unroll
        for (int q=0;q<4;++q) cp[(long)q*N] = OM ? f2h(v[q]) : f2bf(v[q]);
      }
  }

  if constexpr (STATS){
    const int hi = lane >> 4;
    // ---- row partials: max & sumexp over this wave's 64 cols ----
#pragma unroll
    for (int m=0;m<8;++m){
      f32x4 mx = acc[m][0];
#pragma unroll
      for (int n=1;n<4;++n)
#pragma unroll
        for (int q=0;q<4;++q) mx[q] = fmaxf(mx[q], acc[m][n][q]);
#pragma unroll
      for (int off=1; off<16; off<<=1)
#pragma unroll
        for (int q=0;q<4;++q) mx[q] = fmaxf(mx[q], __shfl_xor(mx[q], off));
      f32x4 sm = (f32x4){0.f,0.f,0.f,0.f};
#pragma unroll
      for (int n=0;n<4;++n)
#pragma unroll
        for (int q=0;q<4;++q) sm[q] += __expf(acc[m][n][q] - mx[q]);
#pragma unroll
      for (int off=1; off<16; off<<=1)
#pragma unroll
        for (int q=0;q<4;++q) sm[q] += __shfl_xor(sm[q], off);
      if (fr == 0){
        const int nb = by_*4 + wn;                             // 0..31
        const long rb = ((long)bz*32 + nb)*2048 + brow + wm*128 + m*16 + hi*4;
#pragma unroll
        for (int q=0;q<4;++q){ rpmax[rb+q] = mx[q]; rpsum[rb+q] = sm[q]; }
      }
    }
    // ---- col partials: max & sumexp over this wave's 128 rows ----
#pragma unroll
    for (int n=0;n<4;++n){
      float mx = acc[0][n][0];
#pragma unroll
      for (int m=0;m<8;++m)
#pragma unroll
        for (int q=0;q<4;++q) mx = fmaxf(mx, acc[m][n][q]);
      mx = fmaxf(mx, __shfl_xor(mx, 16));
      mx = fmaxf(mx, __shfl_xor(mx, 32));
      float sm = 0.f;
#pragma unroll
      for (int m=0;m<8;++m)
#pragma unroll
        for (int q=0;q<4;++q) sm += __expf(acc[m][n][q] - mx);
      sm += __shfl_xor(sm, 16);
      sm += __shfl_xor(sm, 32);
      if (hi == 0){
        const int mb = bx_*2 + wm;                             // 0..15
        const long cb = ((long)bz*16 + mb)*2048 + bcol + wn*64 + n*16 + fr;
        cpmax[cb] = mx; cpsum[cb] = sm;
      }
    }
  }
}

// ---- combine split-softmax partials -> exact rmax/rinv (y=0) & cmax/cinv (y=1) ----
__global__ __launch_bounds__(256) void k_combine(
    const float* __restrict__ rpmax, const float* __restrict__ rpsum,
    const float* __restrict__ cpmax, const float* __restrict__ cpsum,
    float* __restrict__ rmax, float* __restrict__ rinv,
    float* __restrict__ cmax, float* __restrict__ cinv)
{
  const long i = (long)blockIdx.x*256 + threadIdx.x;   // 0..16383
  const int b = (int)(i >> 11), r = (int)(i & 2047);
  if (blockIdx.y == 0){
    const float* pm = rpmax + ((long)b*32)*2048 + r;
    const float* ps = rpsum + ((long)b*32)*2048 + r;
    float m = -3.4e38f;
#pragma unroll
    for (int k=0;k<32;++k) m = fmaxf(m, pm[(long)k*2048]);
    float s = 0.f;
#pragma unroll
    for (int k=0;k<32;++k) s += ps[(long)k*2048] * __expf(pm[(long)k*2048] - m);
    rmax[i] = m; rinv[i] = 1.f / s;
  } else {
    const float* pm = cpmax + ((long)b*16)*2048 + r;
    const float* ps = cpsum + ((long)b*16)*2048 + r;
    float m = -3.4e38f;
#pragma unroll
    for (int k=0;k<16;++k) m = fmaxf(m, pm[(long)k*2048]);
    float s = 0.f;
#pragma unroll
    for (int k=0;k<16;++k) s += ps[(long)k*2048] * __expf(pm[(long)k*2048] - m);
    cmax[i] = m; cinv[i] = 1.f / s;
  }
}

// ---- in-place per-batch transform, VECTORIZED (cvtT2-shaped):
// Wg(fp16 scores) -> P1T (bf16, transposed, in place) and, when P2!=nullptr,
// P2 = row-softmax (bf16, natural layout). bf16x8 row reads (16B/lane),
// 16B P2 writes, col-transform staged in padded LDS tile, transposed
// ushort4 writes (identical pattern to k_cvtT2's proven output loop).
__global__ __launch_bounds__(256) void k_p1t2(u16* __restrict__ Wg, u16* __restrict__ P2,
                                              const float* __restrict__ cmax,
                                              const float* __restrict__ cinv,
                                              const float* __restrict__ rmax,
                                              const float* __restrict__ rinv){
  const int ti = blockIdx.x, tj = blockIdx.y;
  if (tj < ti) return;
  const int b = blockIdx.z;
  u16* S = Wg + (long)b * S1_ * S2_;
  u16* P2b = P2 ? P2 + (long)b * S1_ * S2_ : (u16*)nullptr;
  const int I0 = ti*64, J0 = tj*64;
  __shared__ u16 tA[64][68];
  __shared__ u16 tB[64][68];
  __shared__ float scm[128], sci[128];   // [0:64) cols J0+., [64:128) cols I0+.
  const int tid = threadIdx.x;
  if (tid < 64){ scm[tid] = cmax[b*S2_ + J0 + tid]; sci[tid] = cinv[b*S2_ + J0 + tid]; }
  else if (tid < 128){ scm[tid] = cmax[b*S2_ + I0 + tid - 64]; sci[tid] = cinv[b*S2_ + I0 + tid - 64]; }
  __syncthreads();

  const int r0 = tid >> 3;          // 0..31
  const int c8 = (tid & 7) * 8;     // 0,8,...,56
  // ---- tile A = rows I0+., cols J0+. ----
#pragma unroll
  for (int it = 0; it < 2; ++it){
    const int r = it*32 + r0;
    bf16x8 v = *(const bf16x8*)(S + (long)(I0 + r)*S2_ + J0 + c8);
    const float rm = rmax[b*S1_ + I0 + r], ri = rinv[b*S1_ + I0 + r];
    union { bf16x8 v; uint32_t w[4]; } p2o;
#pragma unroll
    for (int k=0;k<4;++k){
      float x0 = h2f((u16)v[2*k]), x1 = h2f((u16)v[2*k+1]);
      p2o.w[k] = pk2bf(__expf(x0 - rm)*ri, __expf(x1 - rm)*ri);
      tA[r][c8+2*k]   = f2bf(__expf(x0 - scm[c8+2*k])   * sci[c8+2*k]);
      tA[r][c8+2*k+1] = f2bf(__expf(x1 - scm[c8+2*k+1]) * sci[c8+2*k+1]);
    }
    if (P2b) *(bf16x8*)(P2b + (long)(I0 + r)*S2_ + J0 + c8) = p2o.v;
  }
  // ---- tile B = rows J0+., cols I0+. (off-diagonal only) ----
  if (ti != tj){
#pragma unroll
    for (int it = 0; it < 2; ++it){
      const int r = it*32 + r0;
      bf16x8 v = *(const bf16x8*)(S + (long)(J0 + r)*S2_ + I0 + c8);
      const float rm = rmax[b*S1_ + J0 + r], ri = rinv[b*S1_ + J0 + r];
      union { bf16x8 v; uint32_t w[4]; } p2o;
#pragma unroll
      for (int k=0;k<4;++k){
        float x0 = h2f((u16)v[2*k]), x1 = h2f((u16)v[2*k+1]);
        p2o.w[k] = pk2bf(__expf(x0 - rm)*ri, __expf(x1 - rm)*ri);
        tB[r][c8+2*k]   = f2bf(__expf(x0 - scm[64+c8+2*k])   * sci[64+c8+2*k]);
        tB[r][c8+2*k+1] = f2bf(__expf(x1 - scm[64+c8+2*k+1]) * sci[64+c8+2*k+1]);
      }
      if (P2b) *(bf16x8*)(P2b + (long)(J0 + r)*S2_ + I0 + c8) = p2o.v;
    }
  }
  __syncthreads();                    // all reads of S complete before S writes
  // ---- transposed writes: S[J0+c][I0+r] = tA[r][c]; S[I0+c][J0+r] = tB[r][c]
  const int rr = tid >> 4;            // 0..15
  const int c4 = (tid & 15) * 4;      // 0..60
#pragma unroll
  for (int it = 0; it < 4; ++it){
    const int c = it*16 + rr;
    ushort4 o;
    o.x = tA[c4  ][c]; o.y = tA[c4+1][c]; o.z = tA[c4+2][c]; o.w = tA[c4+3][c];
    *(ushort4*)(S + (long)(J0 + c)*S2_ + I0 + c4) = o;
  }
  if (ti != tj){
#pragma unroll
    for (int it = 0; it < 4; ++it){
      const int c = it*16 + rr;
      ushort4 o;
      o.x = tB[c4  ][c]; o.y = tB[c4+1][c]; o.z = tB[c4+2][c]; o.w = tB[c4+3][c];
      *(ushort4*)(S + (long)(I0 + c)*S2_ + J0 + c4) = o;
    }
  }
}

// -------- fallback: hidden_2 = rowsoftmax(scores) @ h2t^T (fused A, 128 tile) --------
__global__ __launch_bounds__(256) void k_gemm_h2(
    const u16* __restrict__ Wg, const u16* __restrict__ Bt, float* __restrict__ C,
    const float* __restrict__ rmax, const float* __restrict__ rinv)
{
  const int b = blockIdx.z;
  const u16* A  = Wg + (long)b * S1_ * S2_;
  const u16* Bp = Bt + (long)b * H_ * S2_;
  float* Cp = C + (long)b * S1_ * H_;

  __shared__ u16 As[128*32];
  __shared__ u16 Bs[128*32];
  const int tid = threadIdx.x, lane = tid & 63, w = tid >> 6;
  const int wr = (w >> 1) * 64, wc = (w & 1) * 64;
  const int brow = blockIdx.x * 128, bcol = blockIdx.y * 128;
  f32x4 acc[4][4];
#pragma unroll
  for (int m=0;m<4;++m)
#pragma unroll
    for (int n=0;n<4;++n) acc[m][n] = (f32x4){0.f,0.f,0.f,0.f};

  const int arow = w*16 + (lane >> 2);
  const int scol = (lane & 3) * 8;
  const u16* gA0 = A + (long)(brow + arow) * S2_ + scol;
  const u16* gA1 = gA0 + (long)64 * S2_;
  const float rm0 = rmax[b*S1_ + brow + arow],      ri0 = rinv[b*S1_ + brow + arow];
  const float rm1 = rmax[b*S1_ + brow + arow + 64], ri1 = rinv[b*S1_ + brow + arow + 64];
  u16* wA0 = As + arow*32 + scol;
  u16* wA1 = As + (arow+64)*32 + scol;

  const u16* gb = Bp + (long)(bcol + arow) * S2_ + scol;
  u16* lB0 = Bs + (w*16)*32;  u16* lB1 = Bs + (64 + w*16)*32;

  const int koff = (lane >> 4) * 8;
  const int fr = lane & 15;

  for (int k0 = 0; k0 < S2_; k0 += 32){
    bf16x8 x0 = *(const bf16x8*)(gA0 + k0);
    bf16x8 x1 = *(const bf16x8*)(gA1 + k0);
    async16(lB0, gb);  async16(lB1, gb + (long)64*S2_);
    gb += 32;
    union { bf16x8 v; uint32_t w4[4]; } y0, y1;
#pragma unroll
    for (int k=0;k<4;++k){
      y0.w4[k] = pk2bf(__expf(h2f((u16)x0[2*k])   - rm0) * ri0,
                       __expf(h2f((u16)x0[2*k+1]) - rm0) * ri0);
      y1.w4[k] = pk2bf(__expf(h2f((u16)x1[2*k])   - rm1) * ri1,
                       __expf(h2f((u16)x1[2*k+1]) - rm1) * ri1);
    }
    *(bf16x8*)wA0 = y0.v;
    *(bf16x8*)wA1 = y1.v;
    __syncthreads();
    bf16x8 af[4], bf[4];
#pragma unroll
    for (int m=0;m<4;++m) af[m] = *(const bf16x8*)(As + (wr + m*16 + fr)*32 + koff);
#pragma unroll
    for (int n=0;n<4;++n) bf[n] = *(const bf16x8*)(Bs + (wc + n*16 + fr)*32 + koff);
#pragma unroll
    for (int m=0;m<4;++m)
#pragma unroll
      for (int n=0;n<4;++n)
        acc[m][n] = __builtin_amdgcn_mfma_f32_16x16x32_bf16(af[m], bf[n], acc[m][n], 0,0,0);
    __syncthreads();
  }
  const int crow = brow + wr + (lane >> 4) * 4;
  const int ccol = bcol + wc + fr;
#pragma unroll
  for (int m=0;m<4;++m)
#pragma unroll
    for (int n=0;n<4;++n){
      f32x4 v = acc[m][n];
      float* cp = Cp + (long)(crow + m*16) * H_ + ccol + n*16;
#pragma unroll
      for (int q=0;q<4;++q) cp[(long)q*H_] = v[q];
    }
}

extern "C" void kernel_launch(void* const* d_in, const int* in_sizes, int n_in,
                              void* d_out, int out_size, void* d_ws, size_t ws_size,
                              hipStream_t stream)
{
  const float* h1 = (const float*)d_in[0];   // hidden1 (B,S1,H) fp32
  const float* h2 = (const float*)d_in[1];   // hidden2 (B,S2,H) fp32
  const float* W  = (const float*)d_in[2];   // W (H,H) fp32
  // bias (d_in[3]): uniform shift of scores -> softmax-invariant: unused.
  float* out0 = (float*)d_out;                        // hidden_1 (B,S2,H) fp32
  float* out1 = out0 + (size_t)B_ * S2_ * H_;         // hidden_2 (B,S1,H) fp32

  const long NE = (long)B_ * S1_ * H_;       // 16.78M
  const long NS = (long)B_ * S1_ * S2_;      // 33.55M

  // ws layout — byte-identical to r10-r15 (proven): stats, Wg, h1t, [P2], [h2t].
  char* ws = (char*)d_ws;
  size_t off = 0;
  float* rmax = (float*)(ws + off); off += (size_t)B_*S1_*4;
  float* rinv = (float*)(ws + off); off += (size_t)B_*S1_*4;
  float* cmax = (float*)(ws + off); off += (size_t)B_*S2_*4;
  float* cinv = (float*)(ws + off); off += (size_t)B_*S2_*4;
  u16* Wg  = (u16*)(ws + off);                       // fp16 scores -> P1T in place
  u16* WTb = Wg;                                     // bf16 W^T, dead before Wg written
  off += (size_t)NS*2;
  u16* h1t = (u16*)(ws + off); off += (size_t)NE*2;  // bf16 h1^T [B][H][S1]

  const bool use_p2 = ws_size >= off + (size_t)NS*2;
  u16* P2 = use_p2 ? (u16*)(ws + off) : (u16*)nullptr;
  size_t off2 = off + (use_p2 ? (size_t)NS*2 : 0);
  const bool ws_h2t = ws_size >= off2 + (size_t)NE*2;

  u16* h1b = (u16*)out0;
  u16* h2b = (u16*)out0 + NE;
  u16* h2t = ws_h2t ? (u16*)(ws + off2) : (u16*)out0;
  u16* Qb  = (u16*)out1;
  // split-softmax partials live in out1's dead SECOND half (6 MB of 33.5 MB):
  float* rpmax = (float*)((u16*)out1 + NE);                 // [8][32][2048]
  float* rpsum = rpmax + (size_t)B_*32*2048;
  float* cpmax = rpsum + (size_t)B_*32*2048;                // [8][16][2048]
  float* cpsum = cpmax + (size_t)B_*16*2048;

  if (ws_h2t){
    // merged dual-tensor cvt+transpose (one launch, z=16)
    k_cvtT2m<<<dim3(16,32,16), 256, 0, stream>>>(h1, h1b, h1t, h2, h2b, h2t, S1_, H_);
  } else {
    k_cvtT2<<<dim3(16,32,8), 256, 0, stream>>>(h1, h1b, h1t, S1_, H_);
    k_cvt_bf16<<<dim3(4096), 256, 0, stream>>>(h2, h2b, NE);
  }
  k_tcvt<<<dim3(32,32,1), 256, 0, stream>>>(W, WTb, H_, H_);
  // Q = h1b @ WTb^T  (M=S1,N=H,K=H) -> bf16 (out1 first half)
  k_gemm256<0,false><<<dim3(8, 4, 8), 512, 0, stream>>>(h1b, WTb, Qb, S1_, H_, H_,
        (long)S1_*H_, 0L, (long)S1_*H_, nullptr, nullptr, nullptr, nullptr);
  if (!ws_h2t){
    k_tcvt<<<dim3(32,64,8), 256, 0, stream>>>(h2, h2t, S2_, H_);
  }
  // scores = Qb @ h2b^T -> fp16 Wg; epilogue emits split-softmax partials
  k_gemm256<1,true><<<dim3(8, 8, 8), 512, 0, stream>>>(Qb, h2b, Wg, S1_, S2_, H_,
        (long)S1_*H_, (long)S2_*H_, (long)S1_*S2_, rpmax, rpsum, cpmax, cpsum);
  // combine partials -> exact rmax/rinv (rows) and cmax/cinv (cols)
  k_combine<<<dim3(64, 2), 256, 0, stream>>>(rpmax, rpsum, cpmax, cpsum,
                                             rmax, rinv, cmax, cinv);
  if (use_p2){
    // Wg -> P1T (in place) + P2 (row-softmax); then both output GEMMs are plain bt.
    k_p1t2<<<dim3(32,32,8), 256, 0, stream>>>(Wg, P2, cmax, cinv, rmax, rinv);
    // hidden_2 = P2 @ h2t^T -> out1 (overwrites Qb + partials, both dead)
    k_gemm256<2,false><<<dim3(8, 4, 8), 512, 0, stream>>>(P2, h2t, out1, S1_, H_, S2_,
          (long)S1_*S2_, (long)H_*S2_, (long)S1_*H_, nullptr, nullptr, nullptr, nullptr);
  } else {
    // fallback: fused h2 GEMM must read RAW Wg before p1t destroys it
    k_gemm_h2<<<dim3(16, 8, 8), 256, 0, stream>>>(Wg, h2t, out1, rmax, rinv);
    k_p1t2<<<dim3(32,32,8), 256, 0, stream>>>(Wg, (u16*)nullptr, cmax, cinv, rmax, rinv);
  }
  // hidden_1 = P1T @ h1t^T -> out0 (M=S2,N=H,K=S1)
  k_gemm256<2,false><<<dim3(8, 4, 8), 512, 0, stream>>>(Wg, h1t, out0, S2_, H_, S1_,
        (long)S1_*S2_, (long)H_*S1_, (long)S2_*H_, nullptr, nullptr, nullptr, nullptr);
}

// Round 17
// 355.110 us; speedup vs baseline: 1.4113x; 1.0064x over previous
//
#include <hip/hip_runtime.h>
#include <stdint.h>

#define B_  8
#define S1_ 2048
#define S2_ 2048
#define H_  1024

typedef __attribute__((ext_vector_type(8))) short bf16x8;
typedef __attribute__((ext_vector_type(4))) float f32x4;
typedef unsigned short u16;

__device__ __forceinline__ u16 f2bf(float f){
  union { float f; uint32_t v; } x; x.f = f;
  uint32_t r = x.v + 0x7fffu + ((x.v >> 16) & 1u);
  return (u16)(r >> 16);
}
__device__ __forceinline__ u16 f2h(float f){
  union { _Float16 h; u16 u; } c; c.h = (_Float16)f; return c.u;
}
__device__ __forceinline__ float h2f(u16 u){
  union { _Float16 h; u16 u; } c; c.u = u; return (float)c.h;
}
// packed f32x2 -> bf16x2 (RNE), 1 VALU op for 2 elements
__device__ __forceinline__ uint32_t pk2bf(float lo, float hi){
  uint32_t r;
  asm("v_cvt_pk_bf16_f32 %0, %1, %2" : "=v"(r) : "v"(lo), "v"(hi));
  return r;
}
__device__ __forceinline__ void async16(void* lds, const void* g){
  __builtin_amdgcn_global_load_lds(
      (const __attribute__((address_space(1))) uint32_t*)g,
      (__attribute__((address_space(3))) uint32_t*)lds, 16, 0, 0);
}

// ---------------- fp32 -> bf16 copy ----------------
__global__ __launch_bounds__(256) void k_cvt_bf16(const float* __restrict__ in,
                                                  u16* __restrict__ out, long n){
  long i = ((long)blockIdx.x * 256 + threadIdx.x) * 8;
  const long stride = (long)gridDim.x * 256 * 8;
  for (; i < n; i += stride){
    float4 a = *(const float4*)(in + i);
    float4 b = *(const float4*)(in + i + 4);
    union { bf16x8 v; uint32_t w[4]; } o;
    o.w[0] = pk2bf(a.x, a.y); o.w[1] = pk2bf(a.z, a.w);
    o.w[2] = pk2bf(b.x, b.y); o.w[3] = pk2bf(b.z, b.w);
    *(bf16x8*)(out + i) = o.v;
  }
}

// ------- batched fp32 [R][C] -> bf16 [C][R] transpose (32x32, for W) -------
__global__ __launch_bounds__(256) void k_tcvt(const float* __restrict__ in,
                                              u16* __restrict__ out, int R, int Cc){
  __shared__ u16 t[32][33];
  in  += (long)blockIdx.z * R * Cc;
  out += (long)blockIdx.z * R * Cc;
  const int x = threadIdx.x & 31, y0 = threadIdx.x >> 5;
  const int bx = blockIdx.x * 32, by = blockIdx.y * 32;
  for (int r = y0; r < 32; r += 8) t[r][x] = f2bf(in[(long)(by + r) * Cc + bx + x]);
  __syncthreads();
  for (int r = y0; r < 32; r += 8) out[(long)(bx + r) * R + by + x] = t[x][r];
}

// ------- batched fp32 [R][C] -> bf16 copy AND bf16 transpose, 64x64 tiles -------
__global__ __launch_bounds__(256) void k_cvtT2(const float* __restrict__ in,
                                               u16* __restrict__ out_n,
                                               u16* __restrict__ out_t, int R, int Cc){
  __shared__ u16 t[64][68];
  in    += (long)blockIdx.z * R * Cc;
  out_n += (long)blockIdx.z * R * Cc;
  out_t += (long)blockIdx.z * R * Cc;
  const int tid = threadIdx.x;
  const int r0 = tid >> 4;            // 0..15
  const int c4 = (tid & 15) * 4;      // 0,4,...,60
  const int bx = blockIdx.x * 64;     // col base
  const int by = blockIdx.y * 64;     // row base
#pragma unroll
  for (int it = 0; it < 4; ++it){
    const int r = it*16 + r0;
    float4 v = *(const float4*)(in + (long)(by + r)*Cc + bx + c4);
    u16 b0 = f2bf(v.x), b1 = f2bf(v.y), b2 = f2bf(v.z), b3 = f2bf(v.w);
    ushort4 o; o.x = b0; o.y = b1; o.z = b2; o.w = b3;
    *(ushort4*)(out_n + (long)(by + r)*Cc + bx + c4) = o;
    t[r][c4] = b0; t[r][c4+1] = b1; t[r][c4+2] = b2; t[r][c4+3] = b3;
  }
  __syncthreads();
#pragma unroll
  for (int it = 0; it < 4; ++it){
    const int c = it*16 + r0;         // input col = output row
    ushort4 o;
    o.x = t[c4  ][c]; o.y = t[c4+1][c]; o.z = t[c4+2][c]; o.w = t[c4+3][c];
    *(ushort4*)(out_t + (long)(bx + c)*R + by + c4) = o;
  }
}

// ------- merged dual-tensor cvtT2: z<8 -> tensor 1 (batch z), z>=8 -> tensor 2 -------
__global__ __launch_bounds__(256) void k_cvtT2m(
    const float* __restrict__ in1, u16* __restrict__ n1, u16* __restrict__ t1,
    const float* __restrict__ in2, u16* __restrict__ n2, u16* __restrict__ t2,
    int R, int Cc){
  __shared__ u16 t[64][68];
  const int zb = blockIdx.z & 7;
  const bool second = blockIdx.z >= 8;
  const float* in = (second ? in2 : in1) + (long)zb * R * Cc;
  u16* out_n = (second ? n2 : n1) + (long)zb * R * Cc;
  u16* out_t = (second ? t2 : t1) + (long)zb * R * Cc;
  const int tid = threadIdx.x;
  const int r0 = tid >> 4;
  const int c4 = (tid & 15) * 4;
  const int bx = blockIdx.x * 64;
  const int by = blockIdx.y * 64;
#pragma unroll
  for (int it = 0; it < 4; ++it){
    const int r = it*16 + r0;
    float4 v = *(const float4*)(in + (long)(by + r)*Cc + bx + c4);
    u16 b0 = f2bf(v.x), b1 = f2bf(v.y), b2 = f2bf(v.z), b3 = f2bf(v.w);
    ushort4 o; o.x = b0; o.y = b1; o.z = b2; o.w = b3;
    *(ushort4*)(out_n + (long)(by + r)*Cc + bx + c4) = o;
    t[r][c4] = b0; t[r][c4+1] = b1; t[r][c4+2] = b2; t[r][c4+3] = b3;
  }
  __syncthreads();
#pragma unroll
  for (int it = 0; it < 4; ++it){
    const int c = it*16 + r0;
    ushort4 o;
    o.x = t[c4  ][c]; o.y = t[c4+1][c]; o.z = t[c4+2][c]; o.w = t[c4+3][c];
    *(ushort4*)(out_t + (long)(bx + c)*R + by + c4) = o;
  }
}

// ======= 256x256-tile bt-GEMM, BK=64 double-buffer: C = A @ B^T =======
// r17: BK 32->64, 2 LDS buffers (2 x 64 KB), 1-tile-ahead prefetch. Halves
// the per-K sync cost vs r12 (1 vmcnt(0)+1 barrier per 64 K-units); the
// stage is covered by 64 MFMAs so vmcnt(0) is nearly free. Second K-half's
// ds_reads overlap first half's MFMAs via compiler lgkmcnt (same buffer, no
// barrier). Overwrite safety is PROVEN: a buffer is re-staged only one full
// iteration after its frag reads, which complete before that iter's MFMAs
// (compiler lgkm) -> before the barrier; explicit lgkmcnt(0) added too.
// Swizzle for 128B rows: phys slot = logical ^ (row&7) (pre-swizzled global
// source, LDS linear); read slot = (kk*4+hi)^(fr&7) -> 2-way banks (free).
// T1 XCD chunked swizzle. STATS: scores epilogue emits softmax partials.
// OM: 0 bf16 C, 1 fp16 C, 2 fp32 C.
template<int OM, bool STATS>
__global__ __launch_bounds__(512) void k_gemm256(
    const u16* __restrict__ A, const u16* __restrict__ Bm, void* __restrict__ Cv,
    int M, int N, int K, long sA, long sB, long sC,
    float* __restrict__ rpmax, float* __restrict__ rpsum,
    float* __restrict__ cpmax, float* __restrict__ cpsum)
{
  // ---- XCD chunked swizzle (bijective; total blocks % 8 == 0 by grid design)
  const int GX = gridDim.x, GY = gridDim.y;
  const long plane = (long)GX * GY;
  const long tot = plane * gridDim.z;
  const long lin = blockIdx.x + (long)GX * (blockIdx.y + (long)GY * blockIdx.z);
  const long chunk = tot >> 3;
  const long swz = (lin & 7) * chunk + (lin >> 3);
  const int bz = (int)(swz / plane);
  const int rr = (int)(swz % plane);
  const int by_ = rr / GX, bx_ = rr % GX;

  A += (long)bz * sA; Bm += (long)bz * sB;
  __shared__ u16 lds[2 * 32768];          // 2 bufs x (A 256x64 | B 256x64) = 128 KB
  const int tid = threadIdx.x, lane = tid & 63, w = tid >> 6;
  const int wm = w >> 2, wn = w & 3;      // 2 x 4 wave grid
  const int brow = bx_ * 256, bcol = by_ * 256;

  f32x4 acc[8][4];
#pragma unroll
  for (int m=0;m<8;++m)
#pragma unroll
    for (int n=0;n<4;++n) acc[m][n] = (f32x4){0.f,0.f,0.f,0.f};

  const int fr = lane & 15;
  const int hi = lane >> 4;
  // frag read slots (u16 offset within a 128B row), per K-half kk=0/1:
  const int sk0 = (((0*4)+hi) ^ (fr & 7)) * 8;
  const int sk1 = (((1*4)+hi) ^ (fr & 7)) * 8;

  // staging: 8 issues/wave (4 A + 4 B); issue j covers chunks (w*4+j)*64+lane.
  // chunk cc -> row=cc>>3, phys slot=cc&7 holds logical slot (cc&7)^(row&7).
  const u16* gAs[4]; const u16* gBs[4];
#pragma unroll
  for (int j=0;j<4;++j){
    const int cc = (w*4 + j)*64 + lane;
    const int row = cc >> 3;
    const int sl = (cc & 7) ^ (row & 7);
    gAs[j] = A  + (long)(brow + row) * K + sl*8;
    gBs[j] = Bm + (long)(bcol + row) * K + sl*8;
  }
  auto stage = [&](int buf, int t){
    u16* base = lds + buf*32768;
#pragma unroll
    for (int j=0;j<4;++j) async16(base + (w*4+j)*512, gAs[j] + (long)t*64);
#pragma unroll
    for (int j=0;j<4;++j) async16(base + 16384 + (w*4+j)*512, gBs[j] + (long)t*64);
  };
  auto ldfragK = [&](int buf, int sk, bf16x8* a, bf16x8* b){
    const u16* At = lds + buf*32768;
    const u16* Bt = At + 16384;
#pragma unroll
    for (int n=0;n<4;++n) b[n] = *(const bf16x8*)(Bt + (wn*64 + n*16 + fr)*64 + sk);
#pragma unroll
    for (int m=0;m<8;++m) a[m] = *(const bf16x8*)(At + (wm*128 + m*16 + fr)*64 + sk);
  };

  const int NT = K >> 6;                   // K multiple of 64
  stage(0, 0);
  asm volatile("s_waitcnt vmcnt(0)" ::: "memory");
  __builtin_amdgcn_s_barrier();

  for (int t = 0; t < NT; ++t){
    const int cur = t & 1;
    if (t + 1 < NT) stage(cur ^ 1, t + 1);

    bf16x8 a[8], b[4];
    ldfragK(cur, sk0, a, b);
    __builtin_amdgcn_s_setprio(1);
#pragma unroll
    for (int m=0;m<8;++m)
#pragma unroll
      for (int n=0;n<4;++n)
        acc[m][n] = __builtin_amdgcn_mfma_f32_16x16x32_bf16(a[m], b[n], acc[m][n], 0,0,0);
    __builtin_amdgcn_s_setprio(0);

    ldfragK(cur, sk1, a, b);
    __builtin_amdgcn_s_setprio(1);
#pragma unroll
    for (int m=0;m<8;++m)
#pragma unroll
      for (int n=0;n<4;++n)
        acc[m][n] = __builtin_amdgcn_mfma_f32_16x16x32_bf16(a[m], b[n], acc[m][n], 0,0,0);
    __builtin_amdgcn_s_setprio(0);

    if (t + 1 < NT){
      asm volatile("s_waitcnt vmcnt(0)" ::: "memory");    // next tile landed
      asm volatile("s_waitcnt lgkmcnt(0)" ::: "memory");  // all frag reads done
      __builtin_amdgcn_s_barrier();
    }
  }

  const int crow = brow + wm*128 + hi * 4;
  const int ccol = bcol + wn*64 + fr;
  if constexpr (OM == 2){
    float* C = (float*)Cv + (long)bz * sC;
#pragma unroll
    for (int m=0;m<8;++m)
#pragma unroll
      for (int n=0;n<4;++n){
        f32x4 v = acc[m][n];
        float* cp = C + (long)(crow + m*16) * N + ccol + n*16;
#pragma unroll
        for (int q=0;q<4;++q) cp[(long)q*N] = v[q];
      }
  } else {
    u16* C = (u16*)Cv + (long)bz * sC;
#pragma unroll
    for (int m=0;m<8;++m)
#pragma unroll
      for (int n=0;n<4;++n){
        f32x4 v = acc[m][n];
        u16* cp = C + (long)(crow + m*16) * N + ccol + n*16;
#pragma unroll
        for (int q=0;q<4;++q) cp[(long)q*N] = OM ? f2h(v[q]) : f2bf(v[q]);
      }
  }

  if constexpr (STATS){
    // ---- row partials: max & sumexp over this wave's 64 cols ----
#pragma unroll
    for (int m=0;m<8;++m){
      f32x4 mx = acc[m][0];
#pragma unroll
      for (int n=1;n<4;++n)
#pragma unroll
        for (int q=0;q<4;++q) mx[q] = fmaxf(mx[q], acc[m][n][q]);
#pragma unroll
      for (int off=1; off<16; off<<=1)
#pragma unroll
        for (int q=0;q<4;++q) mx[q] = fmaxf(mx[q], __shfl_xor(mx[q], off));
      f32x4 sm = (f32x4){0.f,0.f,0.f,0.f};
#pragma unroll
      for (int n=0;n<4;++n)
#pragma unroll
        for (int q=0;q<4;++q) sm[q] += __expf(acc[m][n][q] - mx[q]);
#pragma unroll
      for (int off=1; off<16; off<<=1)
#pragma unroll
        for (int q=0;q<4;++q) sm[q] += __shfl_xor(sm[q], off);
      if (fr == 0){
        const int nb = by_*4 + wn;                             // 0..31
        const long rb = ((long)bz*32 + nb)*2048 + brow + wm*128 + m*16 + hi*4;
#pragma unroll
        for (int q=0;q<4;++q){ rpmax[rb+q] = mx[q]; rpsum[rb+q] = sm[q]; }
      }
    }
    // ---- col partials: max & sumexp over this wave's 128 rows ----
#pragma unroll
    for (int n=0;n<4;++n){
      float mx = acc[0][n][0];
#pragma unroll
      for (int m=0;m<8;++m)
#pragma unroll
        for (int q=0;q<4;++q) mx = fmaxf(mx, acc[m][n][q]);
      mx = fmaxf(mx, __shfl_xor(mx, 16));
      mx = fmaxf(mx, __shfl_xor(mx, 32));
      float sm = 0.f;
#pragma unroll
      for (int m=0;m<8;++m)
#pragma unroll
        for (int q=0;q<4;++q) sm += __expf(acc[m][n][q] - mx);
      sm += __shfl_xor(sm, 16);
      sm += __shfl_xor(sm, 32);
      if (hi == 0){
        const int mb = bx_*2 + wm;                             // 0..15
        const long cb = ((long)bz*16 + mb)*2048 + bcol + wn*64 + n*16 + fr;
        cpmax[cb] = mx; cpsum[cb] = sm;
      }
    }
  }
}

// ---- combine split-softmax partials -> exact rmax/rinv (y=0) & cmax/cinv (y=1) ----
__global__ __launch_bounds__(256) void k_combine(
    const float* __restrict__ rpmax, const float* __restrict__ rpsum,
    const float* __restrict__ cpmax, const float* __restrict__ cpsum,
    float* __restrict__ rmax, float* __restrict__ rinv,
    float* __restrict__ cmax, float* __restrict__ cinv)
{
  const long i = (long)blockIdx.x*256 + threadIdx.x;   // 0..16383
  const int b = (int)(i >> 11), r = (int)(i & 2047);
  if (blockIdx.y == 0){
    const float* pm = rpmax + ((long)b*32)*2048 + r;
    const float* ps = rpsum + ((long)b*32)*2048 + r;
    float m = -3.4e38f;
#pragma unroll
    for (int k=0;k<32;++k) m = fmaxf(m, pm[(long)k*2048]);
    float s = 0.f;
#pragma unroll
    for (int k=0;k<32;++k) s += ps[(long)k*2048] * __expf(pm[(long)k*2048] - m);
    rmax[i] = m; rinv[i] = 1.f / s;
  } else {
    const float* pm = cpmax + ((long)b*16)*2048 + r;
    const float* ps = cpsum + ((long)b*16)*2048 + r;
    float m = -3.4e38f;
#pragma unroll
    for (int k=0;k<16;++k) m = fmaxf(m, pm[(long)k*2048]);
    float s = 0.f;
#pragma unroll
    for (int k=0;k<16;++k) s += ps[(long)k*2048] * __expf(pm[(long)k*2048] - m);
    cmax[i] = m; cinv[i] = 1.f / s;
  }
}

// ---- in-place per-batch transform, VECTORIZED (cvtT2-shaped):
// Wg(fp16 scores) -> P1T (bf16, transposed, in place) and, when P2!=nullptr,
// P2 = row-softmax (bf16, natural layout).
__global__ __launch_bounds__(256) void k_p1t2(u16* __restrict__ Wg, u16* __restrict__ P2,
                                              const float* __restrict__ cmax,
                                              const float* __restrict__ cinv,
                                              const float* __restrict__ rmax,
                                              const float* __restrict__ rinv){
  const int ti = blockIdx.x, tj = blockIdx.y;
  if (tj < ti) return;
  const int b = blockIdx.z;
  u16* S = Wg + (long)b * S1_ * S2_;
  u16* P2b = P2 ? P2 + (long)b * S1_ * S2_ : (u16*)nullptr;
  const int I0 = ti*64, J0 = tj*64;
  __shared__ u16 tA[64][68];
  __shared__ u16 tB[64][68];
  __shared__ float scm[128], sci[128];   // [0:64) cols J0+., [64:128) cols I0+.
  const int tid = threadIdx.x;
  if (tid < 64){ scm[tid] = cmax[b*S2_ + J0 + tid]; sci[tid] = cinv[b*S2_ + J0 + tid]; }
  else if (tid < 128){ scm[tid] = cmax[b*S2_ + I0 + tid - 64]; sci[tid] = cinv[b*S2_ + I0 + tid - 64]; }
  __syncthreads();

  const int r0 = tid >> 3;          // 0..31
  const int c8 = (tid & 7) * 8;     // 0,8,...,56
  // ---- tile A = rows I0+., cols J0+. ----
#pragma unroll
  for (int it = 0; it < 2; ++it){
    const int r = it*32 + r0;
    bf16x8 v = *(const bf16x8*)(S + (long)(I0 + r)*S2_ + J0 + c8);
    const float rm = rmax[b*S1_ + I0 + r], ri = rinv[b*S1_ + I0 + r];
    union { bf16x8 v; uint32_t w[4]; } p2o;
#pragma unroll
    for (int k=0;k<4;++k){
      float x0 = h2f((u16)v[2*k]), x1 = h2f((u16)v[2*k+1]);
      p2o.w[k] = pk2bf(__expf(x0 - rm)*ri, __expf(x1 - rm)*ri);
      tA[r][c8+2*k]   = f2bf(__expf(x0 - scm[c8+2*k])   * sci[c8+2*k]);
      tA[r][c8+2*k+1] = f2bf(__expf(x1 - scm[c8+2*k+1]) * sci[c8+2*k+1]);
    }
    if (P2b) *(bf16x8*)(P2b + (long)(I0 + r)*S2_ + J0 + c8) = p2o.v;
  }
  // ---- tile B = rows J0+., cols I0+. (off-diagonal only) ----
  if (ti != tj){
#pragma unroll
    for (int it = 0; it < 2; ++it){
      const int r = it*32 + r0;
      bf16x8 v = *(const bf16x8*)(S + (long)(J0 + r)*S2_ + I0 + c8);
      const float rm = rmax[b*S1_ + J0 + r], ri = rinv[b*S1_ + J0 + r];
      union { bf16x8 v; uint32_t w[4]; } p2o;
#pragma unroll
      for (int k=0;k<4;++k){
        float x0 = h2f((u16)v[2*k]), x1 = h2f((u16)v[2*k+1]);
        p2o.w[k] = pk2bf(__expf(x0 - rm)*ri, __expf(x1 - rm)*ri);
        tB[r][c8+2*k]   = f2bf(__expf(x0 - scm[64+c8+2*k])   * sci[64+c8+2*k]);
        tB[r][c8+2*k+1] = f2bf(__expf(x1 - scm[64+c8+2*k+1]) * sci[64+c8+2*k+1]);
      }
      if (P2b) *(bf16x8*)(P2b + (long)(J0 + r)*S2_ + I0 + c8) = p2o.v;
    }
  }
  __syncthreads();                    // all reads of S complete before S writes
  // ---- transposed writes: S[J0+c][I0+r] = tA[r][c]; S[I0+c][J0+r] = tB[r][c]
  const int rr = tid >> 4;            // 0..15
  const int c4 = (tid & 15) * 4;      // 0..60
#pragma unroll
  for (int it = 0; it < 4; ++it){
    const int c = it*16 + rr;
    ushort4 o;
    o.x = tA[c4  ][c]; o.y = tA[c4+1][c]; o.z = tA[c4+2][c]; o.w = tA[c4+3][c];
    *(ushort4*)(S + (long)(J0 + c)*S2_ + I0 + c4) = o;
  }
  if (ti != tj){
#pragma unroll
    for (int it = 0; it < 4; ++it){
      const int c = it*16 + rr;
      ushort4 o;
      o.x = tB[c4  ][c]; o.y = tB[c4+1][c]; o.z = tB[c4+2][c]; o.w = tB[c4+3][c];
      *(ushort4*)(S + (long)(I0 + c)*S2_ + J0 + c4) = o;
    }
  }
}

// -------- fallback: hidden_2 = rowsoftmax(scores) @ h2t^T (fused A, 128 tile) --------
__global__ __launch_bounds__(256) void k_gemm_h2(
    const u16* __restrict__ Wg, const u16* __restrict__ Bt, float* __restrict__ C,
    const float* __restrict__ rmax, const float* __restrict__ rinv)
{
  const int b = blockIdx.z;
  const u16* A  = Wg + (long)b * S1_ * S2_;
  const u16* Bp = Bt + (long)b * H_ * S2_;
  float* Cp = C + (long)b * S1_ * H_;

  __shared__ u16 As[128*32];
  __shared__ u16 Bs[128*32];
  const int tid = threadIdx.x, lane = tid & 63, w = tid >> 6;
  const int wr = (w >> 1) * 64, wc = (w & 1) * 64;
  const int brow = blockIdx.x * 128, bcol = blockIdx.y * 128;
  f32x4 acc[4][4];
#pragma unroll
  for (int m=0;m<4;++m)
#pragma unroll
    for (int n=0;n<4;++n) acc[m][n] = (f32x4){0.f,0.f,0.f,0.f};

  const int arow = w*16 + (lane >> 2);
  const int scol = (lane & 3) * 8;
  const u16* gA0 = A + (long)(brow + arow) * S2_ + scol;
  const u16* gA1 = gA0 + (long)64 * S2_;
  const float rm0 = rmax[b*S1_ + brow + arow],      ri0 = rinv[b*S1_ + brow + arow];
  const float rm1 = rmax[b*S1_ + brow + arow + 64], ri1 = rinv[b*S1_ + brow + arow + 64];
  u16* wA0 = As + arow*32 + scol;
  u16* wA1 = As + (arow+64)*32 + scol;

  const u16* gb = Bp + (long)(bcol + arow) * S2_ + scol;
  u16* lB0 = Bs + (w*16)*32;  u16* lB1 = Bs + (64 + w*16)*32;

  const int koff = (lane >> 4) * 8;
  const int fr = lane & 15;

  for (int k0 = 0; k0 < S2_; k0 += 32){
    bf16x8 x0 = *(const bf16x8*)(gA0 + k0);
    bf16x8 x1 = *(const bf16x8*)(gA1 + k0);
    async16(lB0, gb);  async16(lB1, gb + (long)64*S2_);
    gb += 32;
    union { bf16x8 v; uint32_t w4[4]; } y0, y1;
#pragma unroll
    for (int k=0;k<4;++k){
      y0.w4[k] = pk2bf(__expf(h2f((u16)x0[2*k])   - rm0) * ri0,
                       __expf(h2f((u16)x0[2*k+1]) - rm0) * ri0);
      y1.w4[k] = pk2bf(__expf(h2f((u16)x1[2*k])   - rm1) * ri1,
                       __expf(h2f((u16)x1[2*k+1]) - rm1) * ri1);
    }
    *(bf16x8*)wA0 = y0.v;
    *(bf16x8*)wA1 = y1.v;
    __syncthreads();
    bf16x8 af[4], bf[4];
#pragma unroll
    for (int m=0;m<4;++m) af[m] = *(const bf16x8*)(As + (wr + m*16 + fr)*32 + koff);
#pragma unroll
    for (int n=0;n<4;++n) bf[n] = *(const bf16x8*)(Bs + (wc + n*16 + fr)*32 + koff);
#pragma unroll
    for (int m=0;m<4;++m)
#pragma unroll
      for (int n=0;n<4;++n)
        acc[m][n] = __builtin_amdgcn_mfma_f32_16x16x32_bf16(af[m], bf[n], acc[m][n], 0,0,0);
    __syncthreads();
  }
  const int crow = brow + wr + (lane >> 4) * 4;
  const int ccol = bcol + wc + fr;
#pragma unroll
  for (int m=0;m<4;++m)
#pragma unroll
    for (int n=0;n<4;++n){
      f32x4 v = acc[m][n];
      float* cp = Cp + (long)(crow + m*16) * H_ + ccol + n*16;
#pragma unroll
      for (int q=0;q<4;++q) cp[(long)q*H_] = v[q];
    }
}

extern "C" void kernel_launch(void* const* d_in, const int* in_sizes, int n_in,
                              void* d_out, int out_size, void* d_ws, size_t ws_size,
                              hipStream_t stream)
{
  const float* h1 = (const float*)d_in[0];   // hidden1 (B,S1,H) fp32
  const float* h2 = (const float*)d_in[1];   // hidden2 (B,S2,H) fp32
  const float* W  = (const float*)d_in[2];   // W (H,H) fp32
  // bias (d_in[3]): uniform shift of scores -> softmax-invariant: unused.
  float* out0 = (float*)d_out;                        // hidden_1 (B,S2,H) fp32
  float* out1 = out0 + (size_t)B_ * S2_ * H_;         // hidden_2 (B,S1,H) fp32

  const long NE = (long)B_ * S1_ * H_;       // 16.78M
  const long NS = (long)B_ * S1_ * S2_;      // 33.55M

  // ws layout — byte-identical to r10-r16 (proven): stats, Wg, h1t, [P2], [h2t].
  char* ws = (char*)d_ws;
  size_t off = 0;
  float* rmax = (float*)(ws + off); off += (size_t)B_*S1_*4;
  float* rinv = (float*)(ws + off); off += (size_t)B_*S1_*4;
  float* cmax = (float*)(ws + off); off += (size_t)B_*S2_*4;
  float* cinv = (float*)(ws + off); off += (size_t)B_*S2_*4;
  u16* Wg  = (u16*)(ws + off);                       // fp16 scores -> P1T in place
  u16* WTb = Wg;                                     // bf16 W^T, dead before Wg written
  off += (size_t)NS*2;
  u16* h1t = (u16*)(ws + off); off += (size_t)NE*2;  // bf16 h1^T [B][H][S1]

  const bool use_p2 = ws_size >= off + (size_t)NS*2;
  u16* P2 = use_p2 ? (u16*)(ws + off) : (u16*)nullptr;
  size_t off2 = off + (use_p2 ? (size_t)NS*2 : 0);
  const bool ws_h2t = ws_size >= off2 + (size_t)NE*2;

  u16* h1b = (u16*)out0;
  u16* h2b = (u16*)out0 + NE;
  u16* h2t = ws_h2t ? (u16*)(ws + off2) : (u16*)out0;
  u16* Qb  = (u16*)out1;
  // split-softmax partials live in out1's dead SECOND half (6 MB of 33.5 MB):
  float* rpmax = (float*)((u16*)out1 + NE);                 // [8][32][2048]
  float* rpsum = rpmax + (size_t)B_*32*2048;
  float* cpmax = rpsum + (size_t)B_*32*2048;                // [8][16][2048]
  float* cpsum = cpmax + (size_t)B_*16*2048;

  if (ws_h2t){
    k_cvtT2m<<<dim3(16,32,16), 256, 0, stream>>>(h1, h1b, h1t, h2, h2b, h2t, S1_, H_);
  } else {
    k_cvtT2<<<dim3(16,32,8), 256, 0, stream>>>(h1, h1b, h1t, S1_, H_);
    k_cvt_bf16<<<dim3(4096), 256, 0, stream>>>(h2, h2b, NE);
  }
  k_tcvt<<<dim3(32,32,1), 256, 0, stream>>>(W, WTb, H_, H_);
  // Q = h1b @ WTb^T  (M=S1,N=H,K=H) -> bf16 (out1 first half)
  k_gemm256<0,false><<<dim3(8, 4, 8), 512, 0, stream>>>(h1b, WTb, Qb, S1_, H_, H_,
        (long)S1_*H_, 0L, (long)S1_*H_, nullptr, nullptr, nullptr, nullptr);
  if (!ws_h2t){
    k_tcvt<<<dim3(32,64,8), 256, 0, stream>>>(h2, h2t, S2_, H_);
  }
  // scores = Qb @ h2b^T -> fp16 Wg; epilogue emits split-softmax partials
  k_gemm256<1,true><<<dim3(8, 8, 8), 512, 0, stream>>>(Qb, h2b, Wg, S1_, S2_, H_,
        (long)S1_*H_, (long)S2_*H_, (long)S1_*S2_, rpmax, rpsum, cpmax, cpsum);
  // combine partials -> exact rmax/rinv (rows) and cmax/cinv (cols)
  k_combine<<<dim3(64, 2), 256, 0, stream>>>(rpmax, rpsum, cpmax, cpsum,
                                             rmax, rinv, cmax, cinv);
  if (use_p2){
    // Wg -> P1T (in place) + P2 (row-softmax); then both output GEMMs are plain bt.
    k_p1t2<<<dim3(32,32,8), 256, 0, stream>>>(Wg, P2, cmax, cinv, rmax, rinv);
    // hidden_2 = P2 @ h2t^T -> out1 (overwrites Qb + partials, both dead)
    k_gemm256<2,false><<<dim3(8, 4, 8), 512, 0, stream>>>(P2, h2t, out1, S1_, H_, S2_,
          (long)S1_*S2_, (long)H_*S2_, (long)S1_*H_, nullptr, nullptr, nullptr, nullptr);
  } else {
    // fallback: fused h2 GEMM must read RAW Wg before p1t destroys it
    k_gemm_h2<<<dim3(16, 8, 8), 256, 0, stream>>>(Wg, h2t, out1, rmax, rinv);
    k_p1t2<<<dim3(32,32,8), 256, 0, stream>>>(Wg, (u16*)nullptr, cmax, cinv, rmax, rinv);
  }
  // hidden_1 = P1T @ h1t^T -> out0 (M=S2,N=H,K=S1)
  k_gemm256<2,false><<<dim3(8, 4, 8), 512, 0, stream>>>(Wg, h1t, out0, S2_, H_, S1_,
        (long)S1_*S2_, (long)H_*S1_, (long)S2_*H_, nullptr, nullptr, nullptr, nullptr);
}